// Round 5
// baseline (1850.929 us; speedup 1.0000x reference)
//
#include <hip/hip_runtime.h>
#include <math.h>

// ---- problem constants ----
#define CH 56          // channels
#define NBD 8          // "B" depth dim
#define HH 192
#define WW 192
#define PLANE (HH*WW)          // 36864
#define S3 (NBD*PLANE)         // 294912 positions per channel
#define NWX 24                 // windows per row/col
#define NTOK 64                // tokens per window
#define DHALF 28               // q/k/v channels
#define DHEAD 14               // per-head dim
// LDS strides
#define XTR 65         // xn transposed [c][tok] stride (odd -> CF)
#define TR  68         // qkv transposed [d][tok] stride (16B-aligned rows)
#define SOP 29         // s_o [tok][o] stride
// FFN MFMA halo: per-branch LDS bytes (100 pixels * 64 ch * 2B)
#define FFN_BR_OFF 12800

typedef __attribute__((ext_vector_type(8))) short short8;
typedef __attribute__((ext_vector_type(4))) float f32x4;

__device__ __forceinline__ int gidx(int c, int b, int y, int x) {
    return ((c * NBD + b) * HH + y) * WW + x;
}

__device__ __forceinline__ unsigned short f2bf(float f) {
    unsigned int u = __float_as_uint(f);
    u = (u + 0x7FFFu + ((u >> 16) & 1u)) >> 16;   // RNE
    return (unsigned short)u;
}

// =====================================================================
// Kernel 1: FA — fused PreNorm + windowed self-attention, per (window,b)
// thread = (row r = tid>>2, sub = tid&3); sub owns 16 sim columns.
// =====================================================================
__global__ __launch_bounds__(256) void fa_kernel(
    const float* __restrict__ x,
    const float* __restrict__ lnw, const float* __restrict__ lnb,
    const float* __restrict__ qkw, const float* __restrict__ vw,
    const float* __restrict__ ow,  const float* __restrict__ ob,
    const float* __restrict__ pcqw, const float* __restrict__ pcqb,
    const float* __restrict__ pckw, const float* __restrict__ pckb,
    const float* __restrict__ m1,  const float* __restrict__ m2a,
    const float* __restrict__ m2b,
    float* __restrict__ x1)
{
    __shared__ float s_xn[CH * XTR];        // LN'd window, [c][tok]
    __shared__ float s_q[DHALF * TR];       // [d][tok]
    __shared__ float s_k[DHALF * TR];
    __shared__ float s_v[DHALF * TR];
    __shared__ float s_o[NTOK * SOP];
    __shared__ float s_Sq[2][NTOK], s_Sk[2][NTOK];
    __shared__ float s_t[NTOK], s_t2[NTOK];
    __shared__ float s_theta;

    const int tid = threadIdx.x;
    const int b   = blockIdx.x & 7;
    const int win = blockIdx.x >> 3;
    const int y0  = (win / NWX) * 8;
    const int x0  = (win % NWX) * 8;

    // ---- load window transposed [c][tok] ----
    for (int i = tid; i < NTOK * CH; i += 256) {
        int c = i >> 6, tok = i & 63;
        s_xn[c * XTR + tok] = x[gidx(c, b, y0 + (tok >> 3), x0 + (tok & 7))];
    }
    __syncthreads();

    // ---- LN per token: 4 lanes/token, one-pass stats, no extra barrier ----
    {
        const int tok = tid >> 2, sub = tid & 3;
        float sm = 0.f, sq = 0.f;
        #pragma unroll
        for (int cc = 0; cc < 14; cc++) {
            float v = s_xn[(sub * 14 + cc) * XTR + tok];
            sm += v; sq += v * v;
        }
        sm += __shfl_xor(sm, 1); sm += __shfl_xor(sm, 2);
        sq += __shfl_xor(sq, 1); sq += __shfl_xor(sq, 2);
        float mu = sm * (1.f / CH);
        float rs = rsqrtf(sq * (1.f / CH) - mu * mu + 1e-5f);
        #pragma unroll
        for (int cc = 0; cc < 14; cc++) {
            int c = sub * 14 + cc;
            s_xn[c * XTR + tok] = (s_xn[c * XTR + tok] - mu) * rs * lnw[c] + lnb[c];
        }
    }
    __syncthreads();

    // ---- projections: 84 outputs x 64 tokens; weights scalar-streamed ----
    for (int i = tid; i < NTOK * 84; i += 256) {
        int o = __builtin_amdgcn_readfirstlane(i >> 6);
        int tok = i & 63;
        const float* wr = (o < 56) ? (qkw + o * 56) : (vw + (o - 56) * 56);
        float acc = 0.f;
        #pragma unroll
        for (int c = 0; c < CH; c++) acc += s_xn[c * XTR + tok] * wr[c];
        if (o < 28)       s_q[o * TR + tok]        = acc;
        else if (o < 56)  s_k[(o - 28) * TR + tok] = acc;
        else              s_v[(o - 56) * TR + tok] = acc;
    }
    __syncthreads();

    // ---- Sq/Sk for both heads ----
    if (tid < 128) {
        int h = tid >> 6, i2 = tid & 63;
        float a = pcqb[0];
        #pragma unroll
        for (int d = 0; d < DHEAD; d++) a += s_q[(h * DHEAD + d) * TR + i2] * pcqw[d];
        s_Sq[h][i2] = a;
    } else {
        int h = (tid - 128) >> 6, j = tid & 63;
        float a = pckb[0];
        #pragma unroll
        for (int d = 0; d < DHEAD; d++) a += s_k[(h * DHEAD + d) * TR + j] * pckw[d];
        s_Sk[h][j] = a;
    }
    __syncthreads();

    const int r = tid >> 2, sub = tid & 3, j0 = sub * 16;

    for (int h = 0; h < 2; h++) {
        const int ho = h * DHEAD;
        // ---- sim into 16 regs ----
        float s[16];
        #pragma unroll
        for (int jj = 0; jj < 16; jj++) s[jj] = 0.f;
        #pragma unroll
        for (int d = 0; d < DHEAD; d++) {
            float qd = s_q[(ho + d) * TR + r];            // 4-lane broadcast
            const float4* kp = (const float4*)(s_k + (ho + d) * TR + j0);
            float kv[16];
            *(float4*)&kv[0]  = kp[0];
            *(float4*)&kv[4]  = kp[1];
            *(float4*)&kv[8]  = kp[2];
            *(float4*)&kv[12] = kp[3];
            #pragma unroll
            for (int jj = 0; jj < 16; jj++) s[jj] += qd * kv[jj];
        }
        // ---- t[r] = sum_{j != r} sim[r][j]*m1[j] ----
        {
            float tp = 0.f;
            #pragma unroll
            for (int jj = 0; jj < 16; jj++) {
                int j = j0 + jj;
                if (j != r) tp += s[jj] * m1[j];
            }
            tp += __shfl_xor(tp, 1); tp += __shfl_xor(tp, 2);
            if (sub == 0) s_t[r] = tp;
        }
        __syncthreads();
        // ---- t2[r] = leaky(sum_i t[i]*m2a[r][i]) ----
        {
            float tp = 0.f;
            #pragma unroll
            for (int ii = 0; ii < 16; ii++) {
                int i2 = j0 + ii;
                tp += s_t[i2] * m2a[r * 64 + i2];
            }
            tp += __shfl_xor(tp, 1); tp += __shfl_xor(tp, 2);
            if (sub == 0) s_t2[r] = (tp > 0.f) ? tp : 0.1f * tp;
        }
        __syncthreads();
        // ---- theta = dot(t2, m2b), wave 0 ----
        if (tid < 64) {
            float a = s_t2[tid] * m2b[tid];
            #pragma unroll
            for (int off = 1; off < 64; off <<= 1) a += __shfl_xor(a, off);
            if (tid == 0) s_theta = a;
        }
        __syncthreads();
        // ---- softmax + threshold mask, all in regs ----
        {
            const float Sqr = s_Sq[h][r];
            const float th  = s_theta;
            float m = -1e30f;
            #pragma unroll
            for (int jj = 0; jj < 16; jj++) {
                s[jj] *= Sqr * s_Sk[h][j0 + jj];
                m = fmaxf(m, s[jj]);
            }
            m = fmaxf(m, __shfl_xor(m, 1));
            m = fmaxf(m, __shfl_xor(m, 2));
            float sum = 0.f;
            #pragma unroll
            for (int jj = 0; jj < 16; jj++) {
                float e = expf(s[jj] - m);
                sum += e;
                s[jj] = (s[jj] > th) ? e : 0.f;
            }
            sum += __shfl_xor(sum, 1); sum += __shfl_xor(sum, 2);
            const float inv = 1.f / sum;
            #pragma unroll
            for (int jj = 0; jj < 16; jj++) s[jj] *= inv;
        }
        // ---- PV from regs; 4-lane reduce; write s_o ----
        {
            float part[14];
            #pragma unroll
            for (int d = 0; d < DHEAD; d++) {
                const float4* vp = (const float4*)(s_v + (ho + d) * TR + j0);
                float vv[16];
                *(float4*)&vv[0]  = vp[0];
                *(float4*)&vv[4]  = vp[1];
                *(float4*)&vv[8]  = vp[2];
                *(float4*)&vv[12] = vp[3];
                float a = 0.f;
                #pragma unroll
                for (int jj = 0; jj < 16; jj++) a += s[jj] * vv[jj];
                part[d] = a;
            }
            #pragma unroll
            for (int d = 0; d < DHEAD; d++) {
                part[d] += __shfl_xor(part[d], 1);
                part[d] += __shfl_xor(part[d], 2);
            }
            #pragma unroll
            for (int k = 0; k < 4; k++) {
                int d = sub + 4 * k;
                if (d < DHEAD) s_o[r * SOP + ho + d] = part[d];
            }
        }
        __syncthreads();
    }

    // ---- epilogue: out-proj + bias + residual ----
    for (int i = tid; i < NTOK * CH; i += 256) {
        int c = __builtin_amdgcn_readfirstlane(i >> 6);
        int tok = i & 63;
        float a = ob[c];
        #pragma unroll
        for (int o = 0; o < DHALF; o++) a += s_o[tok * SOP + o] * ow[c * DHALF + o];
        int g = gidx(c, b, y0 + (tok >> 3), x0 + (tok & 7));
        x1[g] = a + x[g];
    }
}

// =====================================================================
// Kernel 2: LayerNorm over channel dim, fp32 out (for SCA convs)
// =====================================================================
__global__ __launch_bounds__(256) void ln_kernel(
    const float* __restrict__ in, const float* __restrict__ w,
    const float* __restrict__ b, float* __restrict__ outp)
{
    int p = blockIdx.x * 256 + threadIdx.x;
    if (p >= S3) return;
    float v[CH];
    float mu = 0.f;
    #pragma unroll
    for (int c = 0; c < CH; c++) { v[c] = in[(size_t)c * S3 + p]; mu += v[c]; }
    mu *= (1.f / CH);
    float var = 0.f;
    #pragma unroll
    for (int c = 0; c < CH; c++) { float d = v[c] - mu; var += d * d; }
    float rs = rsqrtf(var * (1.f / CH) + 1e-5f);
    #pragma unroll
    for (int c = 0; c < CH; c++)
        outp[(size_t)c * S3 + p] = (v[c] - mu) * rs * w[c] + b[c];
}

// =====================================================================
// Kernel 2b: LayerNorm -> bf16, channel-innermost [p][56] (for FFN MFMA)
// =====================================================================
__global__ __launch_bounds__(256) void ln_bf16_kernel(
    const float* __restrict__ in, const float* __restrict__ w,
    const float* __restrict__ b, unsigned short* __restrict__ outp)
{
    int p = blockIdx.x * 256 + threadIdx.x;
    if (p >= S3) return;
    float v[CH];
    float mu = 0.f;
    #pragma unroll
    for (int c = 0; c < CH; c++) { v[c] = in[(size_t)c * S3 + p]; mu += v[c]; }
    mu *= (1.f / CH);
    float var = 0.f;
    #pragma unroll
    for (int c = 0; c < CH; c++) { float d = v[c] - mu; var += d * d; }
    float rs = rsqrtf(var * (1.f / CH) + 1e-5f);
    unsigned int q[28];
    #pragma unroll
    for (int c = 0; c < CH; c += 2) {
        float a0 = (v[c]     - mu) * rs * w[c]     + b[c];
        float a1 = (v[c + 1] - mu) * rs * w[c + 1] + b[c + 1];
        q[c >> 1] = (unsigned int)f2bf(a0) | ((unsigned int)f2bf(a1) << 16);
    }
    uint4* dst = (uint4*)(outp + (size_t)p * 56);
    #pragma unroll
    for (int k = 0; k < 7; k++) {
        uint4 t; t.x = q[k*4]; t.y = q[k*4+1]; t.z = q[k*4+2]; t.w = q[k*4+3];
        dst[k] = t;
    }
}

// =====================================================================
// Kernel 3: grouped 3x3x3 conv, 2-in -> 1-out per group (28 out ch)
// =====================================================================
__global__ __launch_bounds__(256) void conv3_kernel(
    const float* __restrict__ in, const float* __restrict__ w,
    float* __restrict__ outp)
{
    int n = blockIdx.x * 256 + threadIdx.x;
    if (n >= DHALF * S3) return;
    int o = n / S3;
    int r = n - o * S3;
    int z = r / PLANE;
    int t = r - z * PLANE;
    int y = t / WW;
    int xx = t - y * WW;
    float acc = 0.f;
    #pragma unroll
    for (int ic = 0; ic < 2; ic++) {
        const float* ip = in + (size_t)(2 * o + ic) * S3;
        const float* wp = w + (o * 2 + ic) * 27;
        #pragma unroll
        for (int dz = 0; dz < 3; dz++) {
            int zz = z + dz - 1;
            if (zz < 0 || zz >= NBD) continue;
            #pragma unroll
            for (int dy = 0; dy < 3; dy++) {
                int yy = y + dy - 1;
                if (yy < 0 || yy >= HH) continue;
                #pragma unroll
                for (int dx = 0; dx < 3; dx++) {
                    int xc = xx + dx - 1;
                    if (xc < 0 || xc >= WW) continue;
                    acc += ip[zz * PLANE + yy * WW + xc] * wp[dz * 9 + dy * 3 + dx];
                }
            }
        }
    }
    outp[n] = acc;
}

// =====================================================================
// Kernel 4: SCA — windowed cross-attention on precomputed q,k,v
// same register-resident core as fa_kernel.
// =====================================================================
__global__ __launch_bounds__(256) void sca_kernel(
    const float* __restrict__ qb, const float* __restrict__ kb,
    const float* __restrict__ vb, const float* __restrict__ x1,
    const float* __restrict__ ocw,
    const float* __restrict__ pcqw, const float* __restrict__ pcqb,
    const float* __restrict__ pckw, const float* __restrict__ pckb,
    const float* __restrict__ m1,  const float* __restrict__ m2a,
    const float* __restrict__ m2b,
    float* __restrict__ x2)
{
    __shared__ float s_q[DHALF * TR];
    __shared__ float s_k[DHALF * TR];
    __shared__ float s_v[DHALF * TR];
    __shared__ float s_o[NTOK * SOP];
    __shared__ float s_Sq[2][NTOK], s_Sk[2][NTOK];
    __shared__ float s_t[NTOK], s_t2[NTOK];
    __shared__ float s_theta;

    const int tid = threadIdx.x;
    const int b   = blockIdx.x & 7;
    const int win = blockIdx.x >> 3;
    const int y0  = (win / NWX) * 8;
    const int x0  = (win % NWX) * 8;

    // ---- stage q/k/v transposed [o][tok] ----
    for (int i = tid; i < NTOK * DHALF; i += 256) {
        int o = i >> 6, tok = i & 63;
        int g = ((o * NBD + b) * HH + y0 + (tok >> 3)) * WW + x0 + (tok & 7);
        s_q[o * TR + tok] = qb[g];
        s_k[o * TR + tok] = kb[g];
        s_v[o * TR + tok] = vb[g];
    }
    __syncthreads();

    if (tid < 128) {
        int h = tid >> 6, i2 = tid & 63;
        float a = pcqb[0];
        #pragma unroll
        for (int d = 0; d < DHEAD; d++) a += s_q[(h * DHEAD + d) * TR + i2] * pcqw[d];
        s_Sq[h][i2] = a;
    } else {
        int h = (tid - 128) >> 6, j = tid & 63;
        float a = pckb[0];
        #pragma unroll
        for (int d = 0; d < DHEAD; d++) a += s_k[(h * DHEAD + d) * TR + j] * pckw[d];
        s_Sk[h][j] = a;
    }
    __syncthreads();

    const int r = tid >> 2, sub = tid & 3, j0 = sub * 16;

    for (int h = 0; h < 2; h++) {
        const int ho = h * DHEAD;
        float s[16];
        #pragma unroll
        for (int jj = 0; jj < 16; jj++) s[jj] = 0.f;
        #pragma unroll
        for (int d = 0; d < DHEAD; d++) {
            float qd = s_q[(ho + d) * TR + r];
            const float4* kp = (const float4*)(s_k + (ho + d) * TR + j0);
            float kv[16];
            *(float4*)&kv[0]  = kp[0];
            *(float4*)&kv[4]  = kp[1];
            *(float4*)&kv[8]  = kp[2];
            *(float4*)&kv[12] = kp[3];
            #pragma unroll
            for (int jj = 0; jj < 16; jj++) s[jj] += qd * kv[jj];
        }
        {
            float tp = 0.f;
            #pragma unroll
            for (int jj = 0; jj < 16; jj++) {
                int j = j0 + jj;
                if (j != r) tp += s[jj] * m1[j];
            }
            tp += __shfl_xor(tp, 1); tp += __shfl_xor(tp, 2);
            if (sub == 0) s_t[r] = tp;
        }
        __syncthreads();
        {
            float tp = 0.f;
            #pragma unroll
            for (int ii = 0; ii < 16; ii++) {
                int i2 = j0 + ii;
                tp += s_t[i2] * m2a[r * 64 + i2];
            }
            tp += __shfl_xor(tp, 1); tp += __shfl_xor(tp, 2);
            if (sub == 0) s_t2[r] = (tp > 0.f) ? tp : 0.1f * tp;
        }
        __syncthreads();
        if (tid < 64) {
            float a = s_t2[tid] * m2b[tid];
            #pragma unroll
            for (int off = 1; off < 64; off <<= 1) a += __shfl_xor(a, off);
            if (tid == 0) s_theta = a;
        }
        __syncthreads();
        {
            const float Sqr = s_Sq[h][r];
            const float th  = s_theta;
            float m = -1e30f;
            #pragma unroll
            for (int jj = 0; jj < 16; jj++) {
                s[jj] *= Sqr * s_Sk[h][j0 + jj];
                m = fmaxf(m, s[jj]);
            }
            m = fmaxf(m, __shfl_xor(m, 1));
            m = fmaxf(m, __shfl_xor(m, 2));
            float sum = 0.f;
            #pragma unroll
            for (int jj = 0; jj < 16; jj++) {
                float e = expf(s[jj] - m);
                sum += e;
                s[jj] = (s[jj] > th) ? e : 0.f;
            }
            sum += __shfl_xor(sum, 1); sum += __shfl_xor(sum, 2);
            const float inv = 1.f / sum;
            #pragma unroll
            for (int jj = 0; jj < 16; jj++) s[jj] *= inv;
        }
        {
            float part[14];
            #pragma unroll
            for (int d = 0; d < DHEAD; d++) {
                const float4* vp = (const float4*)(s_v + (ho + d) * TR + j0);
                float vv[16];
                *(float4*)&vv[0]  = vp[0];
                *(float4*)&vv[4]  = vp[1];
                *(float4*)&vv[8]  = vp[2];
                *(float4*)&vv[12] = vp[3];
                float a = 0.f;
                #pragma unroll
                for (int jj = 0; jj < 16; jj++) a += s[jj] * vv[jj];
                part[d] = a;
            }
            #pragma unroll
            for (int d = 0; d < DHEAD; d++) {
                part[d] += __shfl_xor(part[d], 1);
                part[d] += __shfl_xor(part[d], 2);
            }
            #pragma unroll
            for (int k = 0; k < 4; k++) {
                int d = sub + 4 * k;
                if (d < DHEAD) s_o[r * SOP + ho + d] = part[d];
            }
        }
        __syncthreads();
    }

    // ---- epilogue: 1x1x1 expand conv + residual ----
    for (int i = tid; i < NTOK * CH; i += 256) {
        int c = i >> 6, tok = i & 63;
        int g = gidx(c, b, y0 + (tok >> 3), x0 + (tok & 7));
        x2[g] = s_o[tok * SOP + (c >> 1)] * ocw[c] + x1[g];
    }
}

// =====================================================================
// Kernel 5a: collapse FFN weights + emit pre-swizzled bf16 A-fragments.
// =====================================================================
__global__ __launch_bounds__(256) void ffn_wprep_frag_kernel(
    const float* __restrict__ w1x, const float* __restrict__ w2x,
    const float* __restrict__ w1l, const float* __restrict__ w2l,
    unsigned short* __restrict__ wfrag)
{
    int idx = blockIdx.x * 256 + threadIdx.x;     // (f, lane)
    if (idx >= 144 * 64) return;
    int f = idx >> 6, lane = idx & 63;
    int br = f / 72;
    int r  = f - br * 72;
    int tap = r >> 3;
    int m   = (r & 7) >> 1;
    int ks  = r & 1;
    const float* w1 = br ? w1l : w1x;
    const float* w2 = br ? w2l : w2x;
    int o  = m * 16 + (lane & 15);
    int c0 = ks * 32 + (lane >> 4) * 8;
    unsigned short vals[8];
    #pragma unroll
    for (int j = 0; j < 8; j++) {
        int c = c0 + j;
        float a = 0.f;
        if (o < 56 && c < 56) {
            #pragma unroll
            for (int jj = 0; jj < 4; jj++)
                a += w2[(o * 4 + jj) * 9 + tap] * w1[(o * 4 + jj) * 56 + c];
        }
        vals[j] = f2bf(a);
    }
    uint4 packed;
    packed.x = (unsigned int)vals[0] | ((unsigned int)vals[1] << 16);
    packed.y = (unsigned int)vals[2] | ((unsigned int)vals[3] << 16);
    packed.z = (unsigned int)vals[4] | ((unsigned int)vals[5] << 16);
    packed.w = (unsigned int)vals[6] | ((unsigned int)vals[7] << 16);
    *(uint4*)(wfrag + (size_t)idx * 8) = packed;
}

// =====================================================================
// Kernel 5b: FFN via MFMA — 9 shifted GEMMs on bf16 LN'd inputs.
// =====================================================================
__global__ __launch_bounds__(256) void ffn_mfma_kernel(
    const unsigned short* __restrict__ xnb,   // LN'd x2, bf16 [p][56]
    const unsigned short* __restrict__ lnb,   // LN'd last, bf16 [p][56]
    const unsigned short* __restrict__ wfrag, // A-fragments
    const float* __restrict__ x2,             // residual fp32 [c][p]
    float* __restrict__ outp)
{
    __shared__ unsigned short s_t[2 * 100 * 64];   // 25.6 KB

    const int tid = threadIdx.x;
    const int z  = blockIdx.x / 576;
    const int t  = blockIdx.x % 576;
    const int ty = t / 24, tx = t % 24;
    const int y0 = ty * 8, x0 = tx * 8;

    for (int i = tid; i < 1600; i += 256) {
        int br = i / 800;
        int r  = i - br * 800;
        int hp = r >> 3, ck = r & 7;
        int hy = hp / 10, hx = hp - hy * 10;
        int y = y0 + hy - 1, xx = x0 + hx - 1;
        uint4 v = {0u, 0u, 0u, 0u};
        if (ck < 7 && y >= 0 && y < HH && xx >= 0 && xx < WW) {
            const unsigned short* src = (br ? lnb : xnb) +
                (size_t)(z * PLANE + y * WW + xx) * 56 + ck * 8;
            v = *(const uint4*)src;
        }
        unsigned int byte = (unsigned int)(br * FFN_BR_OFF + hp * 128 + ((ck ^ (hp & 7)) << 4));
        *(uint4*)((char*)s_t + byte) = v;
    }
    __syncthreads();

    const int wid  = tid >> 6;
    const int lane = tid & 63;
    const int col  = lane & 15;
    const int grp  = lane >> 4;

    f32x4 accx[4], accl[4];
    #pragma unroll
    for (int n = 0; n < 4; n++) {
        accx[n] = (f32x4){0.f, 0.f, 0.f, 0.f};
        accl[n] = (f32x4){0.f, 0.f, 0.f, 0.f};
    }

    const short8* wf = (const short8*)wfrag;

    for (int tap = 0; tap < 9; tap++) {
        int dy = tap / 3, dx = tap - dy * 3;
        short8 ax0 = wf[(tap * 8 + wid * 2 + 0) * 64 + lane];
        short8 ax1 = wf[(tap * 8 + wid * 2 + 1) * 64 + lane];
        short8 al0 = wf[(72 + tap * 8 + wid * 2 + 0) * 64 + lane];
        short8 al1 = wf[(72 + tap * 8 + wid * 2 + 1) * 64 + lane];
        #pragma unroll
        for (int nt = 0; nt < 4; nt++) {
            int pix = nt * 16 + col;
            int py = pix >> 3, px = pix & 7;
            int hp = (py + dy) * 10 + (px + dx);
            unsigned int base = (unsigned int)(hp * 128);
            unsigned int sw = (unsigned int)(hp & 7);
            unsigned int o0 = base + ((grp ^ sw) << 4);
            short8 bx0 = *(const short8*)((const char*)s_t + o0);
            short8 bl0 = *(const short8*)((const char*)s_t + FFN_BR_OFF + o0);
            accx[nt] = __builtin_amdgcn_mfma_f32_16x16x32_bf16(ax0, bx0, accx[nt], 0, 0, 0);
            accl[nt] = __builtin_amdgcn_mfma_f32_16x16x32_bf16(al0, bl0, accl[nt], 0, 0, 0);
            unsigned int o1 = base + (((4u + grp) ^ sw) << 4);
            short8 bx1 = *(const short8*)((const char*)s_t + o1);
            short8 bl1 = *(const short8*)((const char*)s_t + FFN_BR_OFF + o1);
            accx[nt] = __builtin_amdgcn_mfma_f32_16x16x32_bf16(ax1, bx1, accx[nt], 0, 0, 0);
            accl[nt] = __builtin_amdgcn_mfma_f32_16x16x32_bf16(al1, bl1, accl[nt], 0, 0, 0);
        }
    }

    #pragma unroll
    for (int nt = 0; nt < 4; nt++) {
        int pix = nt * 16 + col;
        int py = pix >> 3, px = pix & 7;
        int p = z * PLANE + (y0 + py) * WW + (x0 + px);
        #pragma unroll
        for (int reg = 0; reg < 4; reg++) {
            int o = wid * 16 + grp * 4 + reg;
            if (o < 56) {
                float lv = accl[nt][reg];
                float ge = 0.5f * lv * (1.f + erff(lv * 0.70710678118654752f));
                size_t g = (size_t)o * S3 + p;
                outp[g] = accx[nt][reg] * ge + x2[g];
            }
        }
    }
}

// =====================================================================
extern "C" void kernel_launch(void* const* d_in, const int* in_sizes, int n_in,
                              void* d_out, int out_size, void* d_ws, size_t ws_size,
                              hipStream_t stream)
{
    (void)in_sizes; (void)n_in; (void)out_size; (void)ws_size;
    const float* x         = (const float*)d_in[0];
    const float* last      = (const float*)d_in[1];
    const float* fa_ln_w   = (const float*)d_in[2];
    const float* fa_ln_b   = (const float*)d_in[3];
    const float* fa_qk_w   = (const float*)d_in[4];
    const float* fa_v_w    = (const float*)d_in[5];
    const float* fa_out_w  = (const float*)d_in[6];
    const float* fa_out_b  = (const float*)d_in[7];
    const float* fa_pcq_w  = (const float*)d_in[8];
    const float* fa_pcq_b  = (const float*)d_in[9];
    const float* fa_pck_w  = (const float*)d_in[10];
    const float* fa_pck_b  = (const float*)d_in[11];
    const float* fa_m1_w   = (const float*)d_in[12];
    const float* fa_m2a_w  = (const float*)d_in[13];
    const float* fa_m2b_w  = (const float*)d_in[14];
    const float* sca_ln1_w = (const float*)d_in[15];
    const float* sca_ln1_b = (const float*)d_in[16];
    const float* sca_ln2_w = (const float*)d_in[17];
    const float* sca_ln2_b = (const float*)d_in[18];
    const float* sca_q_w   = (const float*)d_in[19];
    const float* sca_k_w   = (const float*)d_in[20];
    const float* sca_v_w   = (const float*)d_in[21];
    const float* sca_out_w = (const float*)d_in[22];
    const float* sca_pcq_w = (const float*)d_in[23];
    const float* sca_pcq_b = (const float*)d_in[24];
    const float* sca_pck_w = (const float*)d_in[25];
    const float* sca_pck_b = (const float*)d_in[26];
    const float* sca_m1_w  = (const float*)d_in[27];
    const float* sca_m2a_w = (const float*)d_in[28];
    const float* sca_m2b_w = (const float*)d_in[29];
    const float* ffn_ln1_w = (const float*)d_in[30];
    const float* ffn_ln1_b = (const float*)d_in[31];
    const float* ffn_ln2_w = (const float*)d_in[32];
    const float* ffn_ln2_b = (const float*)d_in[33];
    const float* ffn_x1_w  = (const float*)d_in[34];
    const float* ffn_x2_w  = (const float*)d_in[35];
    const float* ffn_l1_w  = (const float*)d_in[36];
    const float* ffn_l2_w  = (const float*)d_in[37];
    float* out = (float*)d_out;
    float* ws  = (float*)d_ws;

    const size_t FULL = (size_t)CH * S3;      // 16,515,072 floats
    const size_t HALF = (size_t)DHALF * S3;
    float* x1    = ws;                        // FA output (freed after sca)
    float* lnbuf = ws + FULL;                 // LN scratch -> x2
    float* qb    = lnbuf + FULL;
    float* kb    = qb + HALF;
    float* vb    = kb + HALF;
    unsigned short* wfrag = (unsigned short*)(vb + HALF);  // 147 KB
    float* x2    = lnbuf;
    unsigned short* xnb = (unsigned short*)ws;         // bytes [0, 33MB)
    unsigned short* lnbb = (unsigned short*)ws + FULL; // bytes [33MB, 66MB)

    ffn_wprep_frag_kernel<<<dim3(36), dim3(256), 0, stream>>>(
        ffn_x1_w, ffn_x2_w, ffn_l1_w, ffn_l2_w, wfrag);

    fa_kernel<<<dim3(4608), dim3(256), 0, stream>>>(
        x, fa_ln_w, fa_ln_b, fa_qk_w, fa_v_w, fa_out_w, fa_out_b,
        fa_pcq_w, fa_pcq_b, fa_pck_w, fa_pck_b, fa_m1_w, fa_m2a_w, fa_m2b_w, x1);

    ln_kernel<<<dim3(S3 / 256), dim3(256), 0, stream>>>(x1, sca_ln1_w, sca_ln1_b, lnbuf);
    conv3_kernel<<<dim3(DHALF * S3 / 256), dim3(256), 0, stream>>>(lnbuf, sca_q_w, qb);
    ln_kernel<<<dim3(S3 / 256), dim3(256), 0, stream>>>(last, sca_ln2_w, sca_ln2_b, lnbuf);
    conv3_kernel<<<dim3(DHALF * S3 / 256), dim3(256), 0, stream>>>(lnbuf, sca_k_w, kb);
    conv3_kernel<<<dim3(DHALF * S3 / 256), dim3(256), 0, stream>>>(lnbuf, sca_v_w, vb);

    sca_kernel<<<dim3(4608), dim3(256), 0, stream>>>(
        qb, kb, vb, x1, sca_out_w,
        sca_pcq_w, sca_pcq_b, sca_pck_w, sca_pck_b, sca_m1_w, sca_m2a_w, sca_m2b_w, x2);

    ln_bf16_kernel<<<dim3(S3 / 256), dim3(256), 0, stream>>>(x2,   ffn_ln1_w, ffn_ln1_b, xnb);
    ln_bf16_kernel<<<dim3(S3 / 256), dim3(256), 0, stream>>>(last, ffn_ln2_w, ffn_ln2_b, lnbb);
    ffn_mfma_kernel<<<dim3(4608), dim3(256), 0, stream>>>(xnb, lnbb, wfrag, x2, out);
}

// Round 6
// 1753.446 us; speedup vs baseline: 1.0556x; 1.0556x over previous
//
#include <hip/hip_runtime.h>
#include <math.h>

// ---- problem constants ----
#define CH 56          // channels
#define NBD 8          // "B" depth dim
#define HH 192
#define WW 192
#define PLANE (HH*WW)          // 36864
#define S3 (NBD*PLANE)         // 294912 positions per channel
#define NWX 24                 // windows per row/col
#define NTOK 64                // tokens per window
#define DHALF 28               // q/k/v channels
#define DHEAD 14               // per-head dim
// LDS strides
#define XNP 57         // xn [tok][c] stride
#define TR  68         // qkv transposed [d][tok] stride (16B-aligned rows)
#define SOP 29         // s_o [tok][o] stride
// FFN MFMA halo: per-branch LDS bytes (100 pixels * 64 ch * 2B)
#define FFN_BR_OFF 12800

typedef __attribute__((ext_vector_type(8))) short short8;
typedef __attribute__((ext_vector_type(4))) float f32x4;

__device__ __forceinline__ int gidx(int c, int b, int y, int x) {
    return ((c * NBD + b) * HH + y) * WW + x;
}

__device__ __forceinline__ unsigned short f2bf(float f) {
    unsigned int u = __float_as_uint(f);
    u = (u + 0x7FFFu + ((u >> 16) & 1u)) >> 16;   // RNE
    return (unsigned short)u;
}

// =====================================================================
// Attention core (shared by fa/sca), operating on s_q/s_k/s_v [d][tok]
// thread = (h = tid>>7, r = (tid>>1)&63, sub2 = tid&1).
// Each thread owns 32 columns j = jj*8 + sub2*4 + k (jj<8, k<4):
// float4 LDS reads have only 2 distinct addrs/wave, 4 banks apart -> CF.
// =====================================================================
__device__ __forceinline__ void attn_core(
    const float* s_q, const float* s_k, const float* s_v, float* s_o,
    float s_Sq[2][NTOK], float s_Sk[2][NTOK],
    float s_t[2][NTOK], float s_t2[2][NTOK], float* s_theta,
    const float* __restrict__ m1, const float* __restrict__ m2a,
    const float* __restrict__ m2b,
    int tid)
{
    const int h    = tid >> 7;
    const int r    = (tid >> 1) & 63;
    const int sub2 = tid & 1;
    const int jb   = sub2 * 4;           // float4 offset within 8-group
    const int ho   = h * DHEAD;

    // ---- sim into 32 regs ----
    float s[32];
    #pragma unroll
    for (int q = 0; q < 32; q++) s[q] = 0.f;
    #pragma unroll
    for (int d = 0; d < DHEAD; d++) {
        const float qd = s_q[(ho + d) * TR + r];
        const float* kr = s_k + (ho + d) * TR + jb;
        #pragma unroll
        for (int jj = 0; jj < 8; jj++) {
            float4 kv = *(const float4*)(kr + jj * 8);
            s[jj*4+0] += qd * kv.x;
            s[jj*4+1] += qd * kv.y;
            s[jj*4+2] += qd * kv.z;
            s[jj*4+3] += qd * kv.w;
        }
    }
    // ---- t[h][r] = sum_{j != r} sim[r][j]*m1[j] ----
    {
        float tp = 0.f;
        #pragma unroll
        for (int jj = 0; jj < 8; jj++) {
            float4 mv = *(const float4*)(m1 + jj * 8 + jb);
            int j = jj * 8 + jb;
            tp += (j + 0 != r) ? s[jj*4+0] * mv.x : 0.f;
            tp += (j + 1 != r) ? s[jj*4+1] * mv.y : 0.f;
            tp += (j + 2 != r) ? s[jj*4+2] * mv.z : 0.f;
            tp += (j + 3 != r) ? s[jj*4+3] * mv.w : 0.f;
        }
        tp += __shfl_xor(tp, 1);
        if (sub2 == 0) s_t[h][r] = tp;
    }
    __syncthreads();
    // ---- t2[h][r] = leaky(sum_i t[h][i]*m2a[r][i]) ----
    {
        float tp = 0.f;
        #pragma unroll
        for (int jj = 0; jj < 8; jj++) {
            float4 mv = *(const float4*)(m2a + r * 64 + jj * 8 + jb);
            float4 tv = *(const float4*)(&s_t[h][jj * 8 + jb]);
            tp += tv.x * mv.x + tv.y * mv.y + tv.z * mv.z + tv.w * mv.w;
        }
        tp += __shfl_xor(tp, 1);
        if (sub2 == 0) s_t2[h][r] = (tp > 0.f) ? tp : 0.1f * tp;
    }
    __syncthreads();
    // ---- theta[h] = dot(t2[h], m2b): 2 waves, full-wave reduce ----
    if (tid < 128) {
        int hh2 = tid >> 6, j = tid & 63;
        float a = s_t2[hh2][j] * m2b[j];
        #pragma unroll
        for (int off = 1; off < 64; off <<= 1) a += __shfl_xor(a, off);
        if (j == 0) s_theta[hh2] = a;
    }
    __syncthreads();
    // ---- softmax + threshold mask, in regs ----
    {
        const float Sqr = s_Sq[h][r];
        const float th  = s_theta[h];
        float m = -1e30f;
        #pragma unroll
        for (int jj = 0; jj < 8; jj++) {
            float4 skv = *(const float4*)(&s_Sk[h][jj * 8 + jb]);
            s[jj*4+0] *= Sqr * skv.x;
            s[jj*4+1] *= Sqr * skv.y;
            s[jj*4+2] *= Sqr * skv.z;
            s[jj*4+3] *= Sqr * skv.w;
            m = fmaxf(m, fmaxf(fmaxf(s[jj*4+0], s[jj*4+1]),
                               fmaxf(s[jj*4+2], s[jj*4+3])));
        }
        m = fmaxf(m, __shfl_xor(m, 1));
        float sum = 0.f;
        #pragma unroll
        for (int q = 0; q < 32; q++) {
            float e = expf(s[q] - m);
            sum += e;
            s[q] = (s[q] > th) ? e : 0.f;
        }
        sum += __shfl_xor(sum, 1);
        const float inv = 1.f / sum;
        #pragma unroll
        for (int q = 0; q < 32; q++) s[q] *= inv;
    }
    // ---- PV: part[d] = sum_j attn[r][j]*v[j][d]; 2-lane reduce ----
    {
        float part[DHEAD];
        #pragma unroll
        for (int d = 0; d < DHEAD; d++) {
            const float* vr = s_v + (ho + d) * TR + jb;
            float a = 0.f;
            #pragma unroll
            for (int jj = 0; jj < 8; jj++) {
                float4 vv = *(const float4*)(vr + jj * 8);
                a += s[jj*4+0] * vv.x + s[jj*4+1] * vv.y
                   + s[jj*4+2] * vv.z + s[jj*4+3] * vv.w;
            }
            part[d] = a;
        }
        #pragma unroll
        for (int d = 0; d < DHEAD; d++) part[d] += __shfl_xor(part[d], 1);
        // sub2 splits the 14 d's: 7 each
        #pragma unroll
        for (int dd = 0; dd < 7; dd++) {
            int d = sub2 * 7 + dd;
            s_o[r * SOP + ho + d] = part[d];
        }
    }
    __syncthreads();
}

// =====================================================================
// Kernel 1: FA — fused PreNorm + windowed self-attention, per (window,b)
// =====================================================================
__global__ __launch_bounds__(256) void fa_kernel(
    const float* __restrict__ x,
    const float* __restrict__ lnw, const float* __restrict__ lnb,
    const float* __restrict__ qkw, const float* __restrict__ vw,
    const float* __restrict__ ow,  const float* __restrict__ ob,
    const float* __restrict__ pcqw, const float* __restrict__ pcqb,
    const float* __restrict__ pckw, const float* __restrict__ pckb,
    const float* __restrict__ m1,  const float* __restrict__ m2a,
    const float* __restrict__ m2b,
    float* __restrict__ x1)
{
    __shared__ float s_xn[NTOK * XNP];      // [tok][c]
    __shared__ float s_q[DHALF * TR];       // [d][tok]
    __shared__ float s_k[DHALF * TR];
    __shared__ float s_v[DHALF * TR];
    __shared__ float s_o[NTOK * SOP];
    __shared__ float s_Sq[2][NTOK], s_Sk[2][NTOK];
    __shared__ float s_t[2][NTOK], s_t2[2][NTOK];
    __shared__ float s_theta[2];

    const int tid = threadIdx.x;
    const int b   = blockIdx.x & 7;
    const int win = blockIdx.x >> 3;
    const int y0  = (win / NWX) * 8;
    const int x0  = (win % NWX) * 8;

    // ---- load window [tok][c] ----
    for (int i = tid; i < NTOK * CH; i += 256) {
        int c = i >> 6, tok = i & 63;
        s_xn[tok * XNP + c] = x[gidx(c, b, y0 + (tok >> 3), x0 + (tok & 7))];
    }
    __syncthreads();

    // ---- LN per token: 4 lanes/token, one-pass stats ----
    {
        const int tok = tid >> 2, sub = tid & 3;
        float sm = 0.f, sq = 0.f;
        #pragma unroll
        for (int cc = 0; cc < 14; cc++) {
            float v = s_xn[tok * XNP + sub * 14 + cc];
            sm += v; sq += v * v;
        }
        sm += __shfl_xor(sm, 1); sm += __shfl_xor(sm, 2);
        sq += __shfl_xor(sq, 1); sq += __shfl_xor(sq, 2);
        float mu = sm * (1.f / CH);
        float rs = rsqrtf(sq * (1.f / CH) - mu * mu + 1e-5f);
        #pragma unroll
        for (int cc = 0; cc < 14; cc++) {
            int c = sub * 14 + cc;
            s_xn[tok * XNP + c] = (s_xn[tok * XNP + c] - mu) * rs * lnw[c] + lnb[c];
        }
    }
    __syncthreads();

    // ---- projections: 84 outputs x 64 tokens; weights scalar-streamed;
    //      write transposed [o][tok] ----
    for (int i = tid; i < NTOK * 84; i += 256) {
        int o = __builtin_amdgcn_readfirstlane(i >> 6);
        int tok = i & 63;
        const float* wr = (o < 56) ? (qkw + o * 56) : (vw + (o - 56) * 56);
        float acc = 0.f;
        #pragma unroll
        for (int c = 0; c < CH; c++) acc += s_xn[tok * XNP + c] * wr[c];
        if (o < 28)       s_q[o * TR + tok]        = acc;
        else if (o < 56)  s_k[(o - 28) * TR + tok] = acc;
        else              s_v[(o - 56) * TR + tok] = acc;
    }
    __syncthreads();

    // ---- Sq/Sk for both heads ----
    if (tid < 128) {
        int h = tid >> 6, i2 = tid & 63;
        float a = pcqb[0];
        #pragma unroll
        for (int d = 0; d < DHEAD; d++) a += s_q[(h * DHEAD + d) * TR + i2] * pcqw[d];
        s_Sq[h][i2] = a;
    } else {
        int h = (tid - 128) >> 6, j = tid & 63;
        float a = pckb[0];
        #pragma unroll
        for (int d = 0; d < DHEAD; d++) a += s_k[(h * DHEAD + d) * TR + j] * pckw[d];
        s_Sk[h][j] = a;
    }
    __syncthreads();

    attn_core(s_q, s_k, s_v, s_o, s_Sq, s_Sk, s_t, s_t2, s_theta,
              m1, m2a, m2b, tid);

    // ---- epilogue: out-proj + bias + residual ----
    for (int i = tid; i < NTOK * CH; i += 256) {
        int c = __builtin_amdgcn_readfirstlane(i >> 6);
        int tok = i & 63;
        float a = ob[c];
        #pragma unroll
        for (int o = 0; o < DHALF; o++) a += s_o[tok * SOP + o] * ow[c * DHALF + o];
        int g = gidx(c, b, y0 + (tok >> 3), x0 + (tok & 7));
        x1[g] = a + x[g];
    }
}

// =====================================================================
// Kernel 2: LayerNorm over channel dim, fp32 out (for SCA convs)
// =====================================================================
__global__ __launch_bounds__(256) void ln_kernel(
    const float* __restrict__ in, const float* __restrict__ w,
    const float* __restrict__ b, float* __restrict__ outp)
{
    int p = blockIdx.x * 256 + threadIdx.x;
    if (p >= S3) return;
    float v[CH];
    float mu = 0.f;
    #pragma unroll
    for (int c = 0; c < CH; c++) { v[c] = in[(size_t)c * S3 + p]; mu += v[c]; }
    mu *= (1.f / CH);
    float var = 0.f;
    #pragma unroll
    for (int c = 0; c < CH; c++) { float d = v[c] - mu; var += d * d; }
    float rs = rsqrtf(var * (1.f / CH) + 1e-5f);
    #pragma unroll
    for (int c = 0; c < CH; c++)
        outp[(size_t)c * S3 + p] = (v[c] - mu) * rs * w[c] + b[c];
}

// =====================================================================
// Kernel 2b: LayerNorm -> bf16, channel-innermost [p][56] (for FFN MFMA)
// =====================================================================
__global__ __launch_bounds__(256) void ln_bf16_kernel(
    const float* __restrict__ in, const float* __restrict__ w,
    const float* __restrict__ b, unsigned short* __restrict__ outp)
{
    int p = blockIdx.x * 256 + threadIdx.x;
    if (p >= S3) return;
    float v[CH];
    float mu = 0.f;
    #pragma unroll
    for (int c = 0; c < CH; c++) { v[c] = in[(size_t)c * S3 + p]; mu += v[c]; }
    mu *= (1.f / CH);
    float var = 0.f;
    #pragma unroll
    for (int c = 0; c < CH; c++) { float d = v[c] - mu; var += d * d; }
    float rs = rsqrtf(var * (1.f / CH) + 1e-5f);
    unsigned int q[28];
    #pragma unroll
    for (int c = 0; c < CH; c += 2) {
        float a0 = (v[c]     - mu) * rs * w[c]     + b[c];
        float a1 = (v[c + 1] - mu) * rs * w[c + 1] + b[c + 1];
        q[c >> 1] = (unsigned int)f2bf(a0) | ((unsigned int)f2bf(a1) << 16);
    }
    uint4* dst = (uint4*)(outp + (size_t)p * 56);
    #pragma unroll
    for (int k = 0; k < 7; k++) {
        uint4 t; t.x = q[k*4]; t.y = q[k*4+1]; t.z = q[k*4+2]; t.w = q[k*4+3];
        dst[k] = t;
    }
}

// =====================================================================
// Kernel 3: grouped 3x3x3 conv, 2-in -> 1-out per group (28 out ch)
// =====================================================================
__global__ __launch_bounds__(256) void conv3_kernel(
    const float* __restrict__ in, const float* __restrict__ w,
    float* __restrict__ outp)
{
    int n = blockIdx.x * 256 + threadIdx.x;
    if (n >= DHALF * S3) return;
    int o = n / S3;
    int r = n - o * S3;
    int z = r / PLANE;
    int t = r - z * PLANE;
    int y = t / WW;
    int xx = t - y * WW;
    float acc = 0.f;
    #pragma unroll
    for (int ic = 0; ic < 2; ic++) {
        const float* ip = in + (size_t)(2 * o + ic) * S3;
        const float* wp = w + (o * 2 + ic) * 27;
        #pragma unroll
        for (int dz = 0; dz < 3; dz++) {
            int zz = z + dz - 1;
            if (zz < 0 || zz >= NBD) continue;
            #pragma unroll
            for (int dy = 0; dy < 3; dy++) {
                int yy = y + dy - 1;
                if (yy < 0 || yy >= HH) continue;
                #pragma unroll
                for (int dx = 0; dx < 3; dx++) {
                    int xc = xx + dx - 1;
                    if (xc < 0 || xc >= WW) continue;
                    acc += ip[zz * PLANE + yy * WW + xc] * wp[dz * 9 + dy * 3 + dx];
                }
            }
        }
    }
    outp[n] = acc;
}

// =====================================================================
// Kernel 4: SCA — windowed cross-attention on precomputed q,k,v
// =====================================================================
__global__ __launch_bounds__(256) void sca_kernel(
    const float* __restrict__ qb, const float* __restrict__ kb,
    const float* __restrict__ vb, const float* __restrict__ x1,
    const float* __restrict__ ocw,
    const float* __restrict__ pcqw, const float* __restrict__ pcqb,
    const float* __restrict__ pckw, const float* __restrict__ pckb,
    const float* __restrict__ m1,  const float* __restrict__ m2a,
    const float* __restrict__ m2b,
    float* __restrict__ x2)
{
    __shared__ float s_q[DHALF * TR];
    __shared__ float s_k[DHALF * TR];
    __shared__ float s_v[DHALF * TR];
    __shared__ float s_o[NTOK * SOP];
    __shared__ float s_Sq[2][NTOK], s_Sk[2][NTOK];
    __shared__ float s_t[2][NTOK], s_t2[2][NTOK];
    __shared__ float s_theta[2];

    const int tid = threadIdx.x;
    const int b   = blockIdx.x & 7;
    const int win = blockIdx.x >> 3;
    const int y0  = (win / NWX) * 8;
    const int x0  = (win % NWX) * 8;

    // ---- stage q/k/v transposed [o][tok] ----
    for (int i = tid; i < NTOK * DHALF; i += 256) {
        int o = i >> 6, tok = i & 63;
        int g = ((o * NBD + b) * HH + y0 + (tok >> 3)) * WW + x0 + (tok & 7);
        s_q[o * TR + tok] = qb[g];
        s_k[o * TR + tok] = kb[g];
        s_v[o * TR + tok] = vb[g];
    }
    __syncthreads();

    if (tid < 128) {
        int h = tid >> 6, i2 = tid & 63;
        float a = pcqb[0];
        #pragma unroll
        for (int d = 0; d < DHEAD; d++) a += s_q[(h * DHEAD + d) * TR + i2] * pcqw[d];
        s_Sq[h][i2] = a;
    } else {
        int h = (tid - 128) >> 6, j = tid & 63;
        float a = pckb[0];
        #pragma unroll
        for (int d = 0; d < DHEAD; d++) a += s_k[(h * DHEAD + d) * TR + j] * pckw[d];
        s_Sk[h][j] = a;
    }
    __syncthreads();

    attn_core(s_q, s_k, s_v, s_o, s_Sq, s_Sk, s_t, s_t2, s_theta,
              m1, m2a, m2b, tid);

    // ---- epilogue: 1x1x1 expand conv + residual ----
    for (int i = tid; i < NTOK * CH; i += 256) {
        int c = i >> 6, tok = i & 63;
        int g = gidx(c, b, y0 + (tok >> 3), x0 + (tok & 7));
        x2[g] = s_o[tok * SOP + (c >> 1)] * ocw[c] + x1[g];
    }
}

// =====================================================================
// Kernel 5a: collapse FFN weights + emit pre-swizzled bf16 A-fragments.
// =====================================================================
__global__ __launch_bounds__(256) void ffn_wprep_frag_kernel(
    const float* __restrict__ w1x, const float* __restrict__ w2x,
    const float* __restrict__ w1l, const float* __restrict__ w2l,
    unsigned short* __restrict__ wfrag)
{
    int idx = blockIdx.x * 256 + threadIdx.x;     // (f, lane)
    if (idx >= 144 * 64) return;
    int f = idx >> 6, lane = idx & 63;
    int br = f / 72;
    int r  = f - br * 72;
    int tap = r >> 3;
    int m   = (r & 7) >> 1;
    int ks  = r & 1;
    const float* w1 = br ? w1l : w1x;
    const float* w2 = br ? w2l : w2x;
    int o  = m * 16 + (lane & 15);
    int c0 = ks * 32 + (lane >> 4) * 8;
    unsigned short vals[8];
    #pragma unroll
    for (int j = 0; j < 8; j++) {
        int c = c0 + j;
        float a = 0.f;
        if (o < 56 && c < 56) {
            #pragma unroll
            for (int jj = 0; jj < 4; jj++)
                a += w2[(o * 4 + jj) * 9 + tap] * w1[(o * 4 + jj) * 56 + c];
        }
        vals[j] = f2bf(a);
    }
    uint4 packed;
    packed.x = (unsigned int)vals[0] | ((unsigned int)vals[1] << 16);
    packed.y = (unsigned int)vals[2] | ((unsigned int)vals[3] << 16);
    packed.z = (unsigned int)vals[4] | ((unsigned int)vals[5] << 16);
    packed.w = (unsigned int)vals[6] | ((unsigned int)vals[7] << 16);
    *(uint4*)(wfrag + (size_t)idx * 8) = packed;
}

// =====================================================================
// Kernel 5b: FFN via MFMA — 9 shifted GEMMs on bf16 LN'd inputs.
// =====================================================================
__global__ __launch_bounds__(256) void ffn_mfma_kernel(
    const unsigned short* __restrict__ xnb,   // LN'd x2, bf16 [p][56]
    const unsigned short* __restrict__ lnb,   // LN'd last, bf16 [p][56]
    const unsigned short* __restrict__ wfrag, // A-fragments
    const float* __restrict__ x2,             // residual fp32 [c][p]
    float* __restrict__ outp)
{
    __shared__ unsigned short s_t[2 * 100 * 64];   // 25.6 KB

    const int tid = threadIdx.x;
    const int z  = blockIdx.x / 576;
    const int t  = blockIdx.x % 576;
    const int ty = t / 24, tx = t % 24;
    const int y0 = ty * 8, x0 = tx * 8;

    for (int i = tid; i < 1600; i += 256) {
        int br = i / 800;
        int r  = i - br * 800;
        int hp = r >> 3, ck = r & 7;
        int hy = hp / 10, hx = hp - hy * 10;
        int y = y0 + hy - 1, xx = x0 + hx - 1;
        uint4 v = {0u, 0u, 0u, 0u};
        if (ck < 7 && y >= 0 && y < HH && xx >= 0 && xx < WW) {
            const unsigned short* src = (br ? lnb : xnb) +
                (size_t)(z * PLANE + y * WW + xx) * 56 + ck * 8;
            v = *(const uint4*)src;
        }
        unsigned int byte = (unsigned int)(br * FFN_BR_OFF + hp * 128 + ((ck ^ (hp & 7)) << 4));
        *(uint4*)((char*)s_t + byte) = v;
    }
    __syncthreads();

    const int wid  = tid >> 6;
    const int lane = tid & 63;
    const int col  = lane & 15;
    const int grp  = lane >> 4;

    f32x4 accx[4], accl[4];
    #pragma unroll
    for (int n = 0; n < 4; n++) {
        accx[n] = (f32x4){0.f, 0.f, 0.f, 0.f};
        accl[n] = (f32x4){0.f, 0.f, 0.f, 0.f};
    }

    const short8* wf = (const short8*)wfrag;

    for (int tap = 0; tap < 9; tap++) {
        int dy = tap / 3, dx = tap - dy * 3;
        short8 ax0 = wf[(tap * 8 + wid * 2 + 0) * 64 + lane];
        short8 ax1 = wf[(tap * 8 + wid * 2 + 1) * 64 + lane];
        short8 al0 = wf[(72 + tap * 8 + wid * 2 + 0) * 64 + lane];
        short8 al1 = wf[(72 + tap * 8 + wid * 2 + 1) * 64 + lane];
        #pragma unroll
        for (int nt = 0; nt < 4; nt++) {
            int pix = nt * 16 + col;
            int py = pix >> 3, px = pix & 7;
            int hp = (py + dy) * 10 + (px + dx);
            unsigned int base = (unsigned int)(hp * 128);
            unsigned int sw = (unsigned int)(hp & 7);
            unsigned int o0 = base + ((grp ^ sw) << 4);
            short8 bx0 = *(const short8*)((const char*)s_t + o0);
            short8 bl0 = *(const short8*)((const char*)s_t + FFN_BR_OFF + o0);
            accx[nt] = __builtin_amdgcn_mfma_f32_16x16x32_bf16(ax0, bx0, accx[nt], 0, 0, 0);
            accl[nt] = __builtin_amdgcn_mfma_f32_16x16x32_bf16(al0, bl0, accl[nt], 0, 0, 0);
            unsigned int o1 = base + (((4u + grp) ^ sw) << 4);
            short8 bx1 = *(const short8*)((const char*)s_t + o1);
            short8 bl1 = *(const short8*)((const char*)s_t + FFN_BR_OFF + o1);
            accx[nt] = __builtin_amdgcn_mfma_f32_16x16x32_bf16(ax1, bx1, accx[nt], 0, 0, 0);
            accl[nt] = __builtin_amdgcn_mfma_f32_16x16x32_bf16(al1, bl1, accl[nt], 0, 0, 0);
        }
    }

    #pragma unroll
    for (int nt = 0; nt < 4; nt++) {
        int pix = nt * 16 + col;
        int py = pix >> 3, px = pix & 7;
        int p = z * PLANE + (y0 + py) * WW + (x0 + px);
        #pragma unroll
        for (int reg = 0; reg < 4; reg++) {
            int o = wid * 16 + grp * 4 + reg;
            if (o < 56) {
                float lv = accl[nt][reg];
                float ge = 0.5f * lv * (1.f + erff(lv * 0.70710678118654752f));
                size_t g = (size_t)o * S3 + p;
                outp[g] = accx[nt][reg] * ge + x2[g];
            }
        }
    }
}

// =====================================================================
extern "C" void kernel_launch(void* const* d_in, const int* in_sizes, int n_in,
                              void* d_out, int out_size, void* d_ws, size_t ws_size,
                              hipStream_t stream)
{
    (void)in_sizes; (void)n_in; (void)out_size; (void)ws_size;
    const float* x         = (const float*)d_in[0];
    const float* last      = (const float*)d_in[1];
    const float* fa_ln_w   = (const float*)d_in[2];
    const float* fa_ln_b   = (const float*)d_in[3];
    const float* fa_qk_w   = (const float*)d_in[4];
    const float* fa_v_w    = (const float*)d_in[5];
    const float* fa_out_w  = (const float*)d_in[6];
    const float* fa_out_b  = (const float*)d_in[7];
    const float* fa_pcq_w  = (const float*)d_in[8];
    const float* fa_pcq_b  = (const float*)d_in[9];
    const float* fa_pck_w  = (const float*)d_in[10];
    const float* fa_pck_b  = (const float*)d_in[11];
    const float* fa_m1_w   = (const float*)d_in[12];
    const float* fa_m2a_w  = (const float*)d_in[13];
    const float* fa_m2b_w  = (const float*)d_in[14];
    const float* sca_ln1_w = (const float*)d_in[15];
    const float* sca_ln1_b = (const float*)d_in[16];
    const float* sca_ln2_w = (const float*)d_in[17];
    const float* sca_ln2_b = (const float*)d_in[18];
    const float* sca_q_w   = (const float*)d_in[19];
    const float* sca_k_w   = (const float*)d_in[20];
    const float* sca_v_w   = (const float*)d_in[21];
    const float* sca_out_w = (const float*)d_in[22];
    const float* sca_pcq_w = (const float*)d_in[23];
    const float* sca_pcq_b = (const float*)d_in[24];
    const float* sca_pck_w = (const float*)d_in[25];
    const float* sca_pck_b = (const float*)d_in[26];
    const float* sca_m1_w  = (const float*)d_in[27];
    const float* sca_m2a_w = (const float*)d_in[28];
    const float* sca_m2b_w = (const float*)d_in[29];
    const float* ffn_ln1_w = (const float*)d_in[30];
    const float* ffn_ln1_b = (const float*)d_in[31];
    const float* ffn_ln2_w = (const float*)d_in[32];
    const float* ffn_ln2_b = (const float*)d_in[33];
    const float* ffn_x1_w  = (const float*)d_in[34];
    const float* ffn_x2_w  = (const float*)d_in[35];
    const float* ffn_l1_w  = (const float*)d_in[36];
    const float* ffn_l2_w  = (const float*)d_in[37];
    float* out = (float*)d_out;
    float* ws  = (float*)d_ws;

    const size_t FULL = (size_t)CH * S3;      // 16,515,072 floats
    const size_t HALF = (size_t)DHALF * S3;
    float* x1    = ws;                        // FA output (freed after sca)
    float* lnbuf = ws + FULL;                 // LN scratch -> x2
    float* qb    = lnbuf + FULL;
    float* kb    = qb + HALF;
    float* vb    = kb + HALF;
    unsigned short* wfrag = (unsigned short*)(vb + HALF);  // 147 KB
    float* x2    = lnbuf;
    unsigned short* xnb = (unsigned short*)ws;         // bytes [0, 33MB)
    unsigned short* lnbb = (unsigned short*)ws + FULL; // bytes [33MB, 66MB)

    ffn_wprep_frag_kernel<<<dim3(36), dim3(256), 0, stream>>>(
        ffn_x1_w, ffn_x2_w, ffn_l1_w, ffn_l2_w, wfrag);

    fa_kernel<<<dim3(4608), dim3(256), 0, stream>>>(
        x, fa_ln_w, fa_ln_b, fa_qk_w, fa_v_w, fa_out_w, fa_out_b,
        fa_pcq_w, fa_pcq_b, fa_pck_w, fa_pck_b, fa_m1_w, fa_m2a_w, fa_m2b_w, x1);

    ln_kernel<<<dim3(S3 / 256), dim3(256), 0, stream>>>(x1, sca_ln1_w, sca_ln1_b, lnbuf);
    conv3_kernel<<<dim3(DHALF * S3 / 256), dim3(256), 0, stream>>>(lnbuf, sca_q_w, qb);
    ln_kernel<<<dim3(S3 / 256), dim3(256), 0, stream>>>(last, sca_ln2_w, sca_ln2_b, lnbuf);
    conv3_kernel<<<dim3(DHALF * S3 / 256), dim3(256), 0, stream>>>(lnbuf, sca_k_w, kb);
    conv3_kernel<<<dim3(DHALF * S3 / 256), dim3(256), 0, stream>>>(lnbuf, sca_v_w, vb);

    sca_kernel<<<dim3(4608), dim3(256), 0, stream>>>(
        qb, kb, vb, x1, sca_out_w,
        sca_pcq_w, sca_pcq_b, sca_pck_w, sca_pck_b, sca_m1_w, sca_m2a_w, sca_m2b_w, x2);

    ln_bf16_kernel<<<dim3(S3 / 256), dim3(256), 0, stream>>>(x2,   ffn_ln1_w, ffn_ln1_b, xnb);
    ln_bf16_kernel<<<dim3(S3 / 256), dim3(256), 0, stream>>>(last, ffn_ln2_w, ffn_ln2_b, lnbb);
    ffn_mfma_kernel<<<dim3(4608), dim3(256), 0, stream>>>(xnb, lnbb, wfrag, x2, out);
}

// Round 10
// 1493.487 us; speedup vs baseline: 1.2393x; 1.1741x over previous
//
#include <hip/hip_runtime.h>
#include <math.h>

// ---- problem constants ----
#define CH 56          // channels
#define NBD 8          // "B" depth dim
#define HH 192
#define WW 192
#define PLANE (HH*WW)          // 36864
#define S3 (NBD*PLANE)         // 294912 positions per channel
#define NWX 24                 // windows per row/col
#define NTOK 64                // tokens per window
#define DHALF 28               // q/k/v channels
#define DHEAD 14               // per-head dim
// LDS padded strides (bank-conflict avoidance)
#define XNP 57
#define QKP 29
#define SIMP 65
// FFN MFMA halo: per-branch LDS bytes (100 pixels * 64 ch * 2B)
#define FFN_BR_OFF 12800

typedef __attribute__((ext_vector_type(8))) short short8;
typedef __attribute__((ext_vector_type(4))) float f32x4;

__device__ __forceinline__ int gidx(int c, int b, int y, int x) {
    return ((c * NBD + b) * HH + y) * WW + x;
}

__device__ __forceinline__ unsigned short f2bf(float f) {
    unsigned int u = __float_as_uint(f);
    u = (u + 0x7FFFu + ((u >> 16) & 1u)) >> 16;   // RNE
    return (unsigned short)u;
}

// =====================================================================
// Kernel 1: FA — fused PreNorm + windowed self-attention, per (window,b)
// R4-verified math; weights streamed from global (scalar s_load), no s_w.
// =====================================================================
__global__ __launch_bounds__(256) void fa_kernel(
    const float* __restrict__ x,
    const float* __restrict__ lnw, const float* __restrict__ lnb,
    const float* __restrict__ qkw, const float* __restrict__ vw,
    const float* __restrict__ ow,  const float* __restrict__ ob,
    const float* __restrict__ pcqw, const float* __restrict__ pcqb,
    const float* __restrict__ pckw, const float* __restrict__ pckb,
    const float* __restrict__ m1,  const float* __restrict__ m2a,
    const float* __restrict__ m2b,
    float* __restrict__ x1)
{
    __shared__ float s_xn[NTOK * XNP];          // LN'd window [tok][c]
    __shared__ float s_q[NTOK * QKP];
    __shared__ float s_k[NTOK * QKP];
    __shared__ float s_v[NTOK * QKP];
    __shared__ float s_sim[NTOK * SIMP];
    __shared__ float s_o[NTOK * DHALF];
    __shared__ float s_mu[NTOK], s_rs[NTOK];
    __shared__ float s_Sq[NTOK], s_Sk[NTOK], s_t[NTOK], s_t2[NTOK];
    __shared__ float s_theta;

    const int tid = threadIdx.x;
    const int b   = blockIdx.x & 7;
    const int win = blockIdx.x >> 3;
    const int y0  = (win / NWX) * 8;
    const int x0  = (win % NWX) * 8;

    // load window (raw)
    for (int i = tid; i < NTOK * CH; i += 256) {
        int c = i >> 6, tok = i & 63;
        s_xn[tok * XNP + c] = x[gidx(c, b, y0 + (tok >> 3), x0 + (tok & 7))];
    }
    __syncthreads();

    // LN stats per token
    if (tid < NTOK) {
        float mu = 0.f;
        #pragma unroll
        for (int c = 0; c < CH; c++) mu += s_xn[tid * XNP + c];
        mu *= (1.f / CH);
        float var = 0.f;
        #pragma unroll
        for (int c = 0; c < CH; c++) { float d = s_xn[tid * XNP + c] - mu; var += d * d; }
        var *= (1.f / CH);
        s_mu[tid] = mu;
        s_rs[tid] = rsqrtf(var + 1e-5f);
    }
    __syncthreads();
    for (int i = tid; i < NTOK * CH; i += 256) {
        int c = i >> 6, tok = i & 63;
        s_xn[tok * XNP + c] = (s_xn[tok * XNP + c] - s_mu[tok]) * s_rs[tok] * lnw[c] + lnb[c];
    }
    __syncthreads();

    // projections: 64 tokens x 84 outputs; weight rows wave-uniform (s_load)
    for (int i = tid; i < NTOK * 84; i += 256) {
        int o = __builtin_amdgcn_readfirstlane(i >> 6);
        int tok = i & 63;
        const float* wr = (o < 56) ? (qkw + o * 56) : (vw + (o - 56) * 56);
        float acc = 0.f;
        #pragma unroll
        for (int c = 0; c < CH; c++) acc += s_xn[tok * XNP + c] * wr[c];
        if (o < 28)       s_q[tok * QKP + o]        = acc;
        else if (o < 56)  s_k[tok * QKP + (o - 28)] = acc;
        else              s_v[tok * QKP + (o - 56)] = acc;
    }
    __syncthreads();

    // heads
    for (int h = 0; h < 2; h++) {
        const int ho = h * DHEAD;
        if (tid < NTOK) {
            float a = pcqb[0];
            #pragma unroll
            for (int d = 0; d < DHEAD; d++) a += s_q[tid * QKP + ho + d] * pcqw[d];
            s_Sq[tid] = a;
        } else if (tid < 2 * NTOK) {
            int j = tid - NTOK;
            float a = pckb[0];
            #pragma unroll
            for (int d = 0; d < DHEAD; d++) a += s_k[j * QKP + ho + d] * pckw[d];
            s_Sk[j] = a;
        }
        __syncthreads();
        // sim[i][j]
        for (int i = tid; i < NTOK * NTOK; i += 256) {
            int r = i >> 6, j = i & 63;
            float a = 0.f;
            #pragma unroll
            for (int d = 0; d < DHEAD; d++)
                a += s_q[r * QKP + ho + d] * s_k[j * QKP + ho + d];
            s_sim[r * SIMP + j] = a;
        }
        __syncthreads();
        // t[i] = sum_{j != i} sim[i][j]*m1[j]
        if (tid < NTOK) {
            float a = 0.f;
            for (int j = 0; j < NTOK; j++)
                if (j != tid) a += s_sim[tid * SIMP + j] * m1[j];
            s_t[tid] = a;
        }
        __syncthreads();
        // t2[j] = leaky_relu(sum_i t[i]*m2a[j][i], 0.1)
        if (tid < NTOK) {
            float a = 0.f;
            for (int i2 = 0; i2 < NTOK; i2++) a += s_t[i2] * m2a[tid * 64 + i2];
            s_t2[tid] = (a > 0.f) ? a : 0.1f * a;
        }
        __syncthreads();
        if (tid == 0) {
            float a = 0.f;
            for (int j = 0; j < NTOK; j++) a += s_t2[j] * m2b[j];
            s_theta = a;
        }
        __syncthreads();
        // sims = sim*Sq[i]*Sk[j]; attn = softmax(sims) * (sims > theta)
        if (tid < NTOK) {
            const float Sqi = s_Sq[tid];
            float m = -1e30f;
            for (int j = 0; j < NTOK; j++) {
                float s = s_sim[tid * SIMP + j] * Sqi * s_Sk[j];
                s_sim[tid * SIMP + j] = s;
                m = fmaxf(m, s);
            }
            float sum = 0.f;
            for (int j = 0; j < NTOK; j++) sum += expf(s_sim[tid * SIMP + j] - m);
            const float inv = 1.f / sum, th = s_theta;
            for (int j = 0; j < NTOK; j++) {
                float s = s_sim[tid * SIMP + j];
                s_sim[tid * SIMP + j] = (s > th) ? expf(s - m) * inv : 0.f;
            }
        }
        __syncthreads();
        // out[i][d] = sum_j attn[i][j]*v[j][d]
        for (int i = tid; i < NTOK * DHEAD; i += 256) {
            int r = i / DHEAD, d = i - r * DHEAD;
            float a = 0.f;
            #pragma unroll
            for (int j = 0; j < NTOK; j++)
                a += s_sim[r * SIMP + j] * s_v[j * QKP + ho + d];
            s_o[r * DHALF + ho + d] = a;
        }
        __syncthreads();
    }

    // epilogue: out-proj (ow from global, wave-uniform rows) + bias + residual
    for (int i = tid; i < NTOK * CH; i += 256) {
        int c = __builtin_amdgcn_readfirstlane(i >> 6);
        int tok = i & 63;
        float a = ob[c];
        #pragma unroll
        for (int o = 0; o < DHALF; o++) a += s_o[tok * DHALF + o] * ow[c * DHALF + o];
        int g = gidx(c, b, y0 + (tok >> 3), x0 + (tok & 7));
        x1[g] = a + x[g];
    }
}

// =====================================================================
// Kernel 2: LayerNorm over channel dim, fp32 out (for SCA convs)
// =====================================================================
__global__ __launch_bounds__(256) void ln_kernel(
    const float* __restrict__ in, const float* __restrict__ w,
    const float* __restrict__ b, float* __restrict__ outp)
{
    int p = blockIdx.x * 256 + threadIdx.x;
    if (p >= S3) return;
    float v[CH];
    float mu = 0.f;
    #pragma unroll
    for (int c = 0; c < CH; c++) { v[c] = in[(size_t)c * S3 + p]; mu += v[c]; }
    mu *= (1.f / CH);
    float var = 0.f;
    #pragma unroll
    for (int c = 0; c < CH; c++) { float d = v[c] - mu; var += d * d; }
    float rs = rsqrtf(var * (1.f / CH) + 1e-5f);
    #pragma unroll
    for (int c = 0; c < CH; c++)
        outp[(size_t)c * S3 + p] = (v[c] - mu) * rs * w[c] + b[c];
}

// =====================================================================
// Kernel 2b: LayerNorm -> bf16, channel-innermost [p][56] (for FFN MFMA)
// =====================================================================
__global__ __launch_bounds__(256) void ln_bf16_kernel(
    const float* __restrict__ in, const float* __restrict__ w,
    const float* __restrict__ b, unsigned short* __restrict__ outp)
{
    int p = blockIdx.x * 256 + threadIdx.x;
    if (p >= S3) return;
    float v[CH];
    float mu = 0.f;
    #pragma unroll
    for (int c = 0; c < CH; c++) { v[c] = in[(size_t)c * S3 + p]; mu += v[c]; }
    mu *= (1.f / CH);
    float var = 0.f;
    #pragma unroll
    for (int c = 0; c < CH; c++) { float d = v[c] - mu; var += d * d; }
    float rs = rsqrtf(var * (1.f / CH) + 1e-5f);
    unsigned int q[28];
    #pragma unroll
    for (int c = 0; c < CH; c += 2) {
        float a0 = (v[c]     - mu) * rs * w[c]     + b[c];
        float a1 = (v[c + 1] - mu) * rs * w[c + 1] + b[c + 1];
        q[c >> 1] = (unsigned int)f2bf(a0) | ((unsigned int)f2bf(a1) << 16);
    }
    uint4* dst = (uint4*)(outp + (size_t)p * 56);
    #pragma unroll
    for (int k = 0; k < 7; k++) {
        uint4 t; t.x = q[k*4]; t.y = q[k*4+1]; t.z = q[k*4+2]; t.w = q[k*4+3];
        dst[k] = t;
    }
}

// =====================================================================
// Kernel 3: grouped 3x3x3 conv, 2-in -> 1-out per group (28 out ch)
// =====================================================================
__global__ __launch_bounds__(256) void conv3_kernel(
    const float* __restrict__ in, const float* __restrict__ w,
    float* __restrict__ outp)
{
    int n = blockIdx.x * 256 + threadIdx.x;
    if (n >= DHALF * S3) return;
    int o = n / S3;
    int r = n - o * S3;
    int z = r / PLANE;
    int t = r - z * PLANE;
    int y = t / WW;
    int xx = t - y * WW;
    float acc = 0.f;
    #pragma unroll
    for (int ic = 0; ic < 2; ic++) {
        const float* ip = in + (size_t)(2 * o + ic) * S3;
        const float* wp = w + (o * 2 + ic) * 27;
        #pragma unroll
        for (int dz = 0; dz < 3; dz++) {
            int zz = z + dz - 1;
            if (zz < 0 || zz >= NBD) continue;
            #pragma unroll
            for (int dy = 0; dy < 3; dy++) {
                int yy = y + dy - 1;
                if (yy < 0 || yy >= HH) continue;
                #pragma unroll
                for (int dx = 0; dx < 3; dx++) {
                    int xc = xx + dx - 1;
                    if (xc < 0 || xc >= WW) continue;
                    acc += ip[zz * PLANE + yy * WW + xc] * wp[dz * 9 + dy * 3 + dx];
                }
            }
        }
    }
    outp[n] = acc;
}

// =====================================================================
// Kernel 3b: dual grouped 3x3x3 conv — same input, two weight sets
// (k and v both read LN'd `last`): one pass, two outputs.
// =====================================================================
__global__ __launch_bounds__(256) void conv3_dual_kernel(
    const float* __restrict__ in,
    const float* __restrict__ wk, const float* __restrict__ wv,
    float* __restrict__ outk, float* __restrict__ outv)
{
    int n = blockIdx.x * 256 + threadIdx.x;
    if (n >= DHALF * S3) return;
    int o = n / S3;
    int r = n - o * S3;
    int z = r / PLANE;
    int t = r - z * PLANE;
    int y = t / WW;
    int xx = t - y * WW;
    float acck = 0.f, accv = 0.f;
    #pragma unroll
    for (int ic = 0; ic < 2; ic++) {
        const float* ip  = in + (size_t)(2 * o + ic) * S3;
        const float* wpk = wk + (o * 2 + ic) * 27;
        const float* wpv = wv + (o * 2 + ic) * 27;
        #pragma unroll
        for (int dz = 0; dz < 3; dz++) {
            int zz = z + dz - 1;
            if (zz < 0 || zz >= NBD) continue;
            #pragma unroll
            for (int dy = 0; dy < 3; dy++) {
                int yy = y + dy - 1;
                if (yy < 0 || yy >= HH) continue;
                #pragma unroll
                for (int dx = 0; dx < 3; dx++) {
                    int xc = xx + dx - 1;
                    if (xc < 0 || xc >= WW) continue;
                    float iv = ip[zz * PLANE + yy * WW + xc];
                    acck += iv * wpk[dz * 9 + dy * 3 + dx];
                    accv += iv * wpv[dz * 9 + dy * 3 + dx];
                }
            }
        }
    }
    outk[n] = acck;
    outv[n] = accv;
}

// =====================================================================
// Kernel 4: SCA — windowed cross-attention on precomputed q,k,v
// (R4-verified, unchanged)
// =====================================================================
__global__ __launch_bounds__(256) void sca_kernel(
    const float* __restrict__ qb, const float* __restrict__ kb,
    const float* __restrict__ vb, const float* __restrict__ x1,
    const float* __restrict__ ocw,
    const float* __restrict__ pcqw, const float* __restrict__ pcqb,
    const float* __restrict__ pckw, const float* __restrict__ pckb,
    const float* __restrict__ m1,  const float* __restrict__ m2a,
    const float* __restrict__ m2b,
    float* __restrict__ x2)
{
    __shared__ float s_q[NTOK * QKP];
    __shared__ float s_k[NTOK * QKP];
    __shared__ float s_v[NTOK * QKP];
    __shared__ float s_sim[NTOK * SIMP];
    __shared__ float s_o[NTOK * DHALF];
    __shared__ float s_Sq[NTOK], s_Sk[NTOK], s_t[NTOK], s_t2[NTOK];
    __shared__ float s_theta;

    const int tid = threadIdx.x;
    const int b   = blockIdx.x & 7;
    const int win = blockIdx.x >> 3;
    const int y0  = (win / NWX) * 8;
    const int x0  = (win % NWX) * 8;

    for (int i = tid; i < NTOK * DHALF; i += 256) {
        int o = i >> 6, tok = i & 63;
        int g = ((o * NBD + b) * HH + y0 + (tok >> 3)) * WW + x0 + (tok & 7);
        s_q[tok * QKP + o] = qb[g];
        s_k[tok * QKP + o] = kb[g];
        s_v[tok * QKP + o] = vb[g];
    }
    __syncthreads();

    for (int h = 0; h < 2; h++) {
        const int ho = h * DHEAD;
        if (tid < NTOK) {
            float a = pcqb[0];
            #pragma unroll
            for (int d = 0; d < DHEAD; d++) a += s_q[tid * QKP + ho + d] * pcqw[d];
            s_Sq[tid] = a;
        } else if (tid < 2 * NTOK) {
            int j = tid - NTOK;
            float a = pckb[0];
            #pragma unroll
            for (int d = 0; d < DHEAD; d++) a += s_k[j * QKP + ho + d] * pckw[d];
            s_Sk[j] = a;
        }
        __syncthreads();
        for (int i = tid; i < NTOK * NTOK; i += 256) {
            int r = i >> 6, j = i & 63;
            float a = 0.f;
            #pragma unroll
            for (int d = 0; d < DHEAD; d++)
                a += s_q[r * QKP + ho + d] * s_k[j * QKP + ho + d];
            s_sim[r * SIMP + j] = a;
        }
        __syncthreads();
        if (tid < NTOK) {
            float a = 0.f;
            for (int j = 0; j < NTOK; j++)
                if (j != tid) a += s_sim[tid * SIMP + j] * m1[j];
            s_t[tid] = a;
        }
        __syncthreads();
        if (tid < NTOK) {
            float a = 0.f;
            for (int i2 = 0; i2 < NTOK; i2++) a += s_t[i2] * m2a[tid * 64 + i2];
            s_t2[tid] = (a > 0.f) ? a : 0.1f * a;
        }
        __syncthreads();
        if (tid == 0) {
            float a = 0.f;
            for (int j = 0; j < NTOK; j++) a += s_t2[j] * m2b[j];
            s_theta = a;
        }
        __syncthreads();
        if (tid < NTOK) {
            const float Sqi = s_Sq[tid];
            float m = -1e30f;
            for (int j = 0; j < NTOK; j++) {
                float s = s_sim[tid * SIMP + j] * Sqi * s_Sk[j];
                s_sim[tid * SIMP + j] = s;
                m = fmaxf(m, s);
            }
            float sum = 0.f;
            for (int j = 0; j < NTOK; j++) sum += expf(s_sim[tid * SIMP + j] - m);
            const float inv = 1.f / sum, th = s_theta;
            for (int j = 0; j < NTOK; j++) {
                float s = s_sim[tid * SIMP + j];
                s_sim[tid * SIMP + j] = (s > th) ? expf(s - m) * inv : 0.f;
            }
        }
        __syncthreads();
        for (int i = tid; i < NTOK * DHEAD; i += 256) {
            int r = i / DHEAD, d = i - r * DHEAD;
            float a = 0.f;
            #pragma unroll
            for (int j = 0; j < NTOK; j++)
                a += s_sim[r * SIMP + j] * s_v[j * QKP + ho + d];
            s_o[r * DHALF + ho + d] = a;
        }
        __syncthreads();
    }

    for (int i = tid; i < NTOK * CH; i += 256) {
        int c = i >> 6, tok = i & 63;
        int g = gidx(c, b, y0 + (tok >> 3), x0 + (tok & 7));
        x2[g] = s_o[tok * DHALF + (c >> 1)] * ocw[c] + x1[g];
    }
}

// =====================================================================
// Kernel 5a: collapse FFN weights + emit pre-swizzled bf16 A-fragments.
// =====================================================================
__global__ __launch_bounds__(256) void ffn_wprep_frag_kernel(
    const float* __restrict__ w1x, const float* __restrict__ w2x,
    const float* __restrict__ w1l, const float* __restrict__ w2l,
    unsigned short* __restrict__ wfrag)
{
    int idx = blockIdx.x * 256 + threadIdx.x;     // (f, lane)
    if (idx >= 144 * 64) return;
    int f = idx >> 6, lane = idx & 63;
    int br = f / 72;
    int r  = f - br * 72;
    int tap = r >> 3;
    int m   = (r & 7) >> 1;
    int ks  = r & 1;
    const float* w1 = br ? w1l : w1x;
    const float* w2 = br ? w2l : w2x;
    int o  = m * 16 + (lane & 15);
    int c0 = ks * 32 + (lane >> 4) * 8;
    unsigned short vals[8];
    #pragma unroll
    for (int j = 0; j < 8; j++) {
        int c = c0 + j;
        float a = 0.f;
        if (o < 56 && c < 56) {
            #pragma unroll
            for (int jj = 0; jj < 4; jj++)
                a += w2[(o * 4 + jj) * 9 + tap] * w1[(o * 4 + jj) * 56 + c];
        }
        vals[j] = f2bf(a);
    }
    uint4 packed;
    packed.x = (unsigned int)vals[0] | ((unsigned int)vals[1] << 16);
    packed.y = (unsigned int)vals[2] | ((unsigned int)vals[3] << 16);
    packed.z = (unsigned int)vals[4] | ((unsigned int)vals[5] << 16);
    packed.w = (unsigned int)vals[6] | ((unsigned int)vals[7] << 16);
    *(uint4*)(wfrag + (size_t)idx * 8) = packed;
}

// =====================================================================
// Kernel 5b: FFN via MFMA — 9 shifted GEMMs on bf16 LN'd inputs.
// =====================================================================
__global__ __launch_bounds__(256) void ffn_mfma_kernel(
    const unsigned short* __restrict__ xnb,   // LN'd x2, bf16 [p][56]
    const unsigned short* __restrict__ lnb,   // LN'd last, bf16 [p][56]
    const unsigned short* __restrict__ wfrag, // A-fragments
    const float* __restrict__ x2,             // residual fp32 [c][p]
    float* __restrict__ outp)
{
    __shared__ unsigned short s_t[2 * 100 * 64];   // 25.6 KB

    const int tid = threadIdx.x;
    const int z  = blockIdx.x / 576;
    const int t  = blockIdx.x % 576;
    const int ty = t / 24, tx = t % 24;
    const int y0 = ty * 8, x0 = tx * 8;

    for (int i = tid; i < 1600; i += 256) {
        int br = i / 800;
        int r  = i - br * 800;
        int hp = r >> 3, ck = r & 7;
        int hy = hp / 10, hx = hp - hy * 10;
        int y = y0 + hy - 1, xx = x0 + hx - 1;
        uint4 v = {0u, 0u, 0u, 0u};
        if (ck < 7 && y >= 0 && y < HH && xx >= 0 && xx < WW) {
            const unsigned short* src = (br ? lnb : xnb) +
                (size_t)(z * PLANE + y * WW + xx) * 56 + ck * 8;
            v = *(const uint4*)src;
        }
        unsigned int byte = (unsigned int)(br * FFN_BR_OFF + hp * 128 + ((ck ^ (hp & 7)) << 4));
        *(uint4*)((char*)s_t + byte) = v;
    }
    __syncthreads();

    const int wid  = tid >> 6;
    const int lane = tid & 63;
    const int col  = lane & 15;
    const int grp  = lane >> 4;

    f32x4 accx[4], accl[4];
    #pragma unroll
    for (int n = 0; n < 4; n++) {
        accx[n] = (f32x4){0.f, 0.f, 0.f, 0.f};
        accl[n] = (f32x4){0.f, 0.f, 0.f, 0.f};
    }

    const short8* wf = (const short8*)wfrag;

    for (int tap = 0; tap < 9; tap++) {
        int dy = tap / 3, dx = tap - dy * 3;
        short8 ax0 = wf[(tap * 8 + wid * 2 + 0) * 64 + lane];
        short8 ax1 = wf[(tap * 8 + wid * 2 + 1) * 64 + lane];
        short8 al0 = wf[(72 + tap * 8 + wid * 2 + 0) * 64 + lane];
        short8 al1 = wf[(72 + tap * 8 + wid * 2 + 1) * 64 + lane];
        #pragma unroll
        for (int nt = 0; nt < 4; nt++) {
            int pix = nt * 16 + col;
            int py = pix >> 3, px = pix & 7;
            int hp = (py + dy) * 10 + (px + dx);
            unsigned int base = (unsigned int)(hp * 128);
            unsigned int sw = (unsigned int)(hp & 7);
            unsigned int o0 = base + ((grp ^ sw) << 4);
            short8 bx0 = *(const short8*)((const char*)s_t + o0);
            short8 bl0 = *(const short8*)((const char*)s_t + FFN_BR_OFF + o0);
            accx[nt] = __builtin_amdgcn_mfma_f32_16x16x32_bf16(ax0, bx0, accx[nt], 0, 0, 0);
            accl[nt] = __builtin_amdgcn_mfma_f32_16x16x32_bf16(al0, bl0, accl[nt], 0, 0, 0);
            unsigned int o1 = base + (((4u + grp) ^ sw) << 4);
            short8 bx1 = *(const short8*)((const char*)s_t + o1);
            short8 bl1 = *(const short8*)((const char*)s_t + FFN_BR_OFF + o1);
            accx[nt] = __builtin_amdgcn_mfma_f32_16x16x32_bf16(ax1, bx1, accx[nt], 0, 0, 0);
            accl[nt] = __builtin_amdgcn_mfma_f32_16x16x32_bf16(al1, bl1, accl[nt], 0, 0, 0);
        }
    }

    #pragma unroll
    for (int nt = 0; nt < 4; nt++) {
        int pix = nt * 16 + col;
        int py = pix >> 3, px = pix & 7;
        int p = z * PLANE + (y0 + py) * WW + (x0 + px);
        #pragma unroll
        for (int reg = 0; reg < 4; reg++) {
            int o = wid * 16 + grp * 4 + reg;
            if (o < 56) {
                float lv = accl[nt][reg];
                float ge = 0.5f * lv * (1.f + erff(lv * 0.70710678118654752f));
                size_t g = (size_t)o * S3 + p;
                outp[g] = accx[nt][reg] * ge + x2[g];
            }
        }
    }
}

// =====================================================================
extern "C" void kernel_launch(void* const* d_in, const int* in_sizes, int n_in,
                              void* d_out, int out_size, void* d_ws, size_t ws_size,
                              hipStream_t stream)
{
    (void)in_sizes; (void)n_in; (void)out_size; (void)ws_size;
    const float* x         = (const float*)d_in[0];
    const float* last      = (const float*)d_in[1];
    const float* fa_ln_w   = (const float*)d_in[2];
    const float* fa_ln_b   = (const float*)d_in[3];
    const float* fa_qk_w   = (const float*)d_in[4];
    const float* fa_v_w    = (const float*)d_in[5];
    const float* fa_out_w  = (const float*)d_in[6];
    const float* fa_out_b  = (const float*)d_in[7];
    const float* fa_pcq_w  = (const float*)d_in[8];
    const float* fa_pcq_b  = (const float*)d_in[9];
    const float* fa_pck_w  = (const float*)d_in[10];
    const float* fa_pck_b  = (const float*)d_in[11];
    const float* fa_m1_w   = (const float*)d_in[12];
    const float* fa_m2a_w  = (const float*)d_in[13];
    const float* fa_m2b_w  = (const float*)d_in[14];
    const float* sca_ln1_w = (const float*)d_in[15];
    const float* sca_ln1_b = (const float*)d_in[16];
    const float* sca_ln2_w = (const float*)d_in[17];
    const float* sca_ln2_b = (const float*)d_in[18];
    const float* sca_q_w   = (const float*)d_in[19];
    const float* sca_k_w   = (const float*)d_in[20];
    const float* sca_v_w   = (const float*)d_in[21];
    const float* sca_out_w = (const float*)d_in[22];
    const float* sca_pcq_w = (const float*)d_in[23];
    const float* sca_pcq_b = (const float*)d_in[24];
    const float* sca_pck_w = (const float*)d_in[25];
    const float* sca_pck_b = (const float*)d_in[26];
    const float* sca_m1_w  = (const float*)d_in[27];
    const float* sca_m2a_w = (const float*)d_in[28];
    const float* sca_m2b_w = (const float*)d_in[29];
    const float* ffn_ln1_w = (const float*)d_in[30];
    const float* ffn_ln1_b = (const float*)d_in[31];
    const float* ffn_ln2_w = (const float*)d_in[32];
    const float* ffn_ln2_b = (const float*)d_in[33];
    const float* ffn_x1_w  = (const float*)d_in[34];
    const float* ffn_x2_w  = (const float*)d_in[35];
    const float* ffn_l1_w  = (const float*)d_in[36];
    const float* ffn_l2_w  = (const float*)d_in[37];
    float* out = (float*)d_out;
    float* ws  = (float*)d_ws;

    const size_t FULL = (size_t)CH * S3;      // 16,515,072 floats
    const size_t HALF = (size_t)DHALF * S3;
    float* x1    = ws;                        // FA output (freed after sca)
    float* lnbuf = ws + FULL;                 // LN scratch -> x2
    float* qb    = lnbuf + FULL;
    float* kb    = qb + HALF;
    float* vb    = kb + HALF;
    unsigned short* wfrag = (unsigned short*)(vb + HALF);  // 147 KB
    float* x2    = lnbuf;
    unsigned short* xnb  = (unsigned short*)ws;        // bytes [0, 33MB)
    unsigned short* lnbb = (unsigned short*)ws + FULL; // bytes [33MB, 66MB)

    // --- FFN weight fragments (independent) ---
    ffn_wprep_frag_kernel<<<dim3(36), dim3(256), 0, stream>>>(
        ffn_x1_w, ffn_x2_w, ffn_l1_w, ffn_l2_w, wfrag);

    // --- FA ---
    fa_kernel<<<dim3(4608), dim3(256), 0, stream>>>(
        x, fa_ln_w, fa_ln_b, fa_qk_w, fa_v_w, fa_out_w, fa_out_b,
        fa_pcq_w, fa_pcq_b, fa_pck_w, fa_pck_b, fa_m1_w, fa_m2a_w, fa_m2b_w, x1);

    // --- SCA: LN + grouped convs (k+v merged: one pass over LN'd last) ---
    ln_kernel<<<dim3(S3 / 256), dim3(256), 0, stream>>>(x1, sca_ln1_w, sca_ln1_b, lnbuf);
    conv3_kernel<<<dim3(DHALF * S3 / 256), dim3(256), 0, stream>>>(lnbuf, sca_q_w, qb);
    ln_kernel<<<dim3(S3 / 256), dim3(256), 0, stream>>>(last, sca_ln2_w, sca_ln2_b, lnbuf);
    conv3_dual_kernel<<<dim3(DHALF * S3 / 256), dim3(256), 0, stream>>>(
        lnbuf, sca_k_w, sca_v_w, kb, vb);

    sca_kernel<<<dim3(4608), dim3(256), 0, stream>>>(
        qb, kb, vb, x1, sca_out_w,
        sca_pcq_w, sca_pcq_b, sca_pck_w, sca_pck_b, sca_m1_w, sca_m2a_w, sca_m2b_w, x2);

    // --- FFN: LN->bf16, then MFMA conv ---
    ln_bf16_kernel<<<dim3(S3 / 256), dim3(256), 0, stream>>>(x2,   ffn_ln1_w, ffn_ln1_b, xnb);
    ln_bf16_kernel<<<dim3(S3 / 256), dim3(256), 0, stream>>>(last, ffn_ln2_w, ffn_ln2_b, lnbb);
    ffn_mfma_kernel<<<dim3(4608), dim3(256), 0, stream>>>(xnb, lnbb, wfrag, x2, out);
}

// Round 11
// 1233.676 us; speedup vs baseline: 1.5003x; 1.2106x over previous
//
#include <hip/hip_runtime.h>
#include <math.h>

// ---- problem constants ----
#define CH 56          // channels
#define NBD 8          // "B" depth dim
#define HH 192
#define WW 192
#define PLANE (HH*WW)          // 36864
#define S3 (NBD*PLANE)         // 294912 positions per channel
#define NWX 24                 // windows per row/col
#define NTOK 64                // tokens per window
#define DHALF 28               // q/k/v channels
#define DHEAD 14               // per-head dim
// LDS padded strides (bank-conflict avoidance)
#define XNP 57
#define QKP 29
#define SIMP 65
// FFN MFMA halo: per-branch LDS bytes (100 pixels * 64 ch * 2B)
#define FFN_BR_OFF 12800

typedef __attribute__((ext_vector_type(8))) short short8;
typedef __attribute__((ext_vector_type(4))) float f32x4;

__device__ __forceinline__ int gidx(int c, int b, int y, int x) {
    return ((c * NBD + b) * HH + y) * WW + x;
}

__device__ __forceinline__ unsigned short f2bf(float f) {
    unsigned int u = __float_as_uint(f);
    u = (u + 0x7FFFu + ((u >> 16) & 1u)) >> 16;   // RNE
    return (unsigned short)u;
}

// =====================================================================
// Kernel 1: FA — fused PreNorm + windowed self-attention, per (window,b)
// R10 math; t/t2/theta/softmax parallelized 4 lanes/row; s_xn pool
// reused for s_o/Sq/Sk/t/t2/theta -> 53.5 KB LDS (3 blocks/CU).
// =====================================================================
__global__ __launch_bounds__(256) void fa_kernel(
    const float* __restrict__ x,
    const float* __restrict__ lnw, const float* __restrict__ lnb,
    const float* __restrict__ qkw, const float* __restrict__ vw,
    const float* __restrict__ ow,  const float* __restrict__ ob,
    const float* __restrict__ pcqw, const float* __restrict__ pcqb,
    const float* __restrict__ pckw, const float* __restrict__ pckb,
    const float* __restrict__ m1,  const float* __restrict__ m2a,
    const float* __restrict__ m2b,
    float* __restrict__ x1)
{
    // pool: s_xn [64][57] (phases 1-3)  ->  s_o[64][28] + Sq/Sk/t/t2/theta
    __shared__ __align__(16) char s_pool[NTOK * XNP * 4];   // 14592 B
    __shared__ float s_q[NTOK * QKP];
    __shared__ float s_k[NTOK * QKP];
    __shared__ float s_v[NTOK * QKP];
    __shared__ float s_sim[NTOK * SIMP];

    float* s_xn = (float*)s_pool;
    float* s_o  = (float*)s_pool;                  // [64][28] = 7168 B
    float* s_Sq = (float*)(s_pool + 7168);         // [64]
    float* s_Sk = (float*)(s_pool + 7424);         // [64]
    float* s_t  = (float*)(s_pool + 7680);         // [64]
    float* s_t2 = (float*)(s_pool + 7936);         // [64]
    float* s_th = (float*)(s_pool + 8192);         // [1]

    const int tid = threadIdx.x;
    const int b   = blockIdx.x & 7;
    const int win = blockIdx.x >> 3;
    const int y0  = (win / NWX) * 8;
    const int x0  = (win % NWX) * 8;

    // ---- load window (raw) ----
    for (int i = tid; i < NTOK * CH; i += 256) {
        int c = i >> 6, tok = i & 63;
        s_xn[tok * XNP + c] = x[gidx(c, b, y0 + (tok >> 3), x0 + (tok & 7))];
    }
    __syncthreads();

    // ---- LN in place: 4 lanes/token, one-pass stats (R6-verified) ----
    {
        const int tok = tid >> 2, sub = tid & 3;
        float sm = 0.f, sq = 0.f;
        #pragma unroll
        for (int cc = 0; cc < 14; cc++) {
            float v = s_xn[tok * XNP + sub * 14 + cc];
            sm += v; sq += v * v;
        }
        sm += __shfl_xor(sm, 1); sm += __shfl_xor(sm, 2);
        sq += __shfl_xor(sq, 1); sq += __shfl_xor(sq, 2);
        float mu = sm * (1.f / CH);
        float rs = rsqrtf(sq * (1.f / CH) - mu * mu + 1e-5f);
        #pragma unroll
        for (int cc = 0; cc < 14; cc++) {
            int c = sub * 14 + cc;
            s_xn[tok * XNP + c] = (s_xn[tok * XNP + c] - mu) * rs * lnw[c] + lnb[c];
        }
    }
    __syncthreads();

    // ---- projections: 84 outputs x 64 tokens; weight rows wave-uniform ----
    for (int i = tid; i < NTOK * 84; i += 256) {
        int o = __builtin_amdgcn_readfirstlane(i >> 6);
        int tok = i & 63;
        const float* wr = (o < 56) ? (qkw + o * 56) : (vw + (o - 56) * 56);
        float acc = 0.f;
        #pragma unroll
        for (int c = 0; c < CH; c++) acc += s_xn[tok * XNP + c] * wr[c];
        if (o < 28)       s_q[tok * QKP + o]        = acc;
        else if (o < 56)  s_k[tok * QKP + (o - 28)] = acc;
        else              s_v[tok * QKP + (o - 56)] = acc;
    }
    __syncthreads();       // s_xn dead from here; pool becomes s_o/Sq/Sk/t/t2/th

    // ---- heads ----
    for (int h = 0; h < 2; h++) {
        const int ho = h * DHEAD;
        if (tid < NTOK) {
            float a = pcqb[0];
            #pragma unroll
            for (int d = 0; d < DHEAD; d++) a += s_q[tid * QKP + ho + d] * pcqw[d];
            s_Sq[tid] = a;
        } else if (tid < 2 * NTOK) {
            int j = tid - NTOK;
            float a = pckb[0];
            #pragma unroll
            for (int d = 0; d < DHEAD; d++) a += s_k[j * QKP + ho + d] * pckw[d];
            s_Sk[j] = a;
        }
        __syncthreads();
        // sim[i][j] (all 256 threads)
        for (int i = tid; i < NTOK * NTOK; i += 256) {
            int r = i >> 6, j = i & 63;
            float a = 0.f;
            #pragma unroll
            for (int d = 0; d < DHEAD; d++)
                a += s_q[r * QKP + ho + d] * s_k[j * QKP + ho + d];
            s_sim[r * SIMP + j] = a;
        }
        __syncthreads();
        // t[r] = sum_{j != r} sim[r][j]*m1[j] — 4 lanes/row
        {
            const int r = tid >> 2, sub = tid & 3;
            float a = 0.f;
            #pragma unroll
            for (int jj = 0; jj < 16; jj++) {
                int j = sub * 16 + jj;
                a += (j != r) ? s_sim[r * SIMP + j] * m1[j] : 0.f;
            }
            a += __shfl_xor(a, 1); a += __shfl_xor(a, 2);
            if (sub == 0) s_t[r] = a;
        }
        __syncthreads();
        // t2[r] = leaky_relu(sum_i t[i]*m2a[r][i]) — 4 lanes/row
        {
            const int r = tid >> 2, sub = tid & 3;
            float a = 0.f;
            #pragma unroll
            for (int jj = 0; jj < 16; jj++) {
                int i2 = sub * 16 + jj;
                a += s_t[i2] * m2a[r * 64 + i2];
            }
            a += __shfl_xor(a, 1); a += __shfl_xor(a, 2);
            if (sub == 0) s_t2[r] = (a > 0.f) ? a : 0.1f * a;
        }
        __syncthreads();
        // theta = dot(t2, m2b) — wave reduce
        if (tid < 64) {
            float a = s_t2[tid] * m2b[tid];
            #pragma unroll
            for (int off = 1; off < 64; off <<= 1) a += __shfl_xor(a, off);
            if (tid == 0) s_th[0] = a;
        }
        __syncthreads();
        // sims = sim*Sq[r]*Sk[j]; attn = softmax * (sims > theta) — 4 lanes/row
        {
            const int r = tid >> 2, sub = tid & 3;
            const float Sqi = s_Sq[r];
            const float th = s_th[0];
            float vals[16];
            float m = -1e30f;
            #pragma unroll
            for (int jj = 0; jj < 16; jj++) {
                float s = s_sim[r * SIMP + sub * 16 + jj] * Sqi * s_Sk[sub * 16 + jj];
                vals[jj] = s;
                m = fmaxf(m, s);
            }
            m = fmaxf(m, __shfl_xor(m, 1));
            m = fmaxf(m, __shfl_xor(m, 2));
            float sum = 0.f;
            #pragma unroll
            for (int jj = 0; jj < 16; jj++) {
                float e = expf(vals[jj] - m);
                sum += e;
                vals[jj] = (vals[jj] > th) ? e : 0.f;
            }
            sum += __shfl_xor(sum, 1); sum += __shfl_xor(sum, 2);
            const float inv = 1.f / sum;
            #pragma unroll
            for (int jj = 0; jj < 16; jj++)
                s_sim[r * SIMP + sub * 16 + jj] = vals[jj] * inv;
        }
        __syncthreads();
        // out[i][d] = sum_j attn[i][j]*v[j][d]
        for (int i = tid; i < NTOK * DHEAD; i += 256) {
            int r = i / DHEAD, d = i - r * DHEAD;
            float a = 0.f;
            #pragma unroll
            for (int j = 0; j < NTOK; j++)
                a += s_sim[r * SIMP + j] * s_v[j * QKP + ho + d];
            s_o[r * DHALF + ho + d] = a;
        }
        __syncthreads();
    }

    // ---- epilogue: out-proj + bias + residual ----
    for (int i = tid; i < NTOK * CH; i += 256) {
        int c = __builtin_amdgcn_readfirstlane(i >> 6);
        int tok = i & 63;
        float a = ob[c];
        #pragma unroll
        for (int o = 0; o < DHALF; o++) a += s_o[tok * DHALF + o] * ow[c * DHALF + o];
        int g = gidx(c, b, y0 + (tok >> 3), x0 + (tok & 7));
        x1[g] = a + x[g];
    }
}

// =====================================================================
// Kernel 2: LayerNorm over channel dim, fp32 out (for SCA convs)
// =====================================================================
__global__ __launch_bounds__(256) void ln_kernel(
    const float* __restrict__ in, const float* __restrict__ w,
    const float* __restrict__ b, float* __restrict__ outp)
{
    int p = blockIdx.x * 256 + threadIdx.x;
    if (p >= S3) return;
    float v[CH];
    float mu = 0.f;
    #pragma unroll
    for (int c = 0; c < CH; c++) { v[c] = in[(size_t)c * S3 + p]; mu += v[c]; }
    mu *= (1.f / CH);
    float var = 0.f;
    #pragma unroll
    for (int c = 0; c < CH; c++) { float d = v[c] - mu; var += d * d; }
    float rs = rsqrtf(var * (1.f / CH) + 1e-5f);
    #pragma unroll
    for (int c = 0; c < CH; c++)
        outp[(size_t)c * S3 + p] = (v[c] - mu) * rs * w[c] + b[c];
}

// =====================================================================
// Kernel 2b: LayerNorm -> bf16, channel-innermost [p][56] (for FFN MFMA)
// =====================================================================
__global__ __launch_bounds__(256) void ln_bf16_kernel(
    const float* __restrict__ in, const float* __restrict__ w,
    const float* __restrict__ b, unsigned short* __restrict__ outp)
{
    int p = blockIdx.x * 256 + threadIdx.x;
    if (p >= S3) return;
    float v[CH];
    float mu = 0.f;
    #pragma unroll
    for (int c = 0; c < CH; c++) { v[c] = in[(size_t)c * S3 + p]; mu += v[c]; }
    mu *= (1.f / CH);
    float var = 0.f;
    #pragma unroll
    for (int c = 0; c < CH; c++) { float d = v[c] - mu; var += d * d; }
    float rs = rsqrtf(var * (1.f / CH) + 1e-5f);
    unsigned int q[28];
    #pragma unroll
    for (int c = 0; c < CH; c += 2) {
        float a0 = (v[c]     - mu) * rs * w[c]     + b[c];
        float a1 = (v[c + 1] - mu) * rs * w[c + 1] + b[c + 1];
        q[c >> 1] = (unsigned int)f2bf(a0) | ((unsigned int)f2bf(a1) << 16);
    }
    uint4* dst = (uint4*)(outp + (size_t)p * 56);
    #pragma unroll
    for (int k = 0; k < 7; k++) {
        uint4 t; t.x = q[k*4]; t.y = q[k*4+1]; t.z = q[k*4+2]; t.w = q[k*4+3];
        dst[k] = t;
    }
}

// =====================================================================
// Kernel 3: grouped 3x3x3 conv, 2-in -> 1-out per group (28 out ch)
// =====================================================================
__global__ __launch_bounds__(256) void conv3_kernel(
    const float* __restrict__ in, const float* __restrict__ w,
    float* __restrict__ outp)
{
    int n = blockIdx.x * 256 + threadIdx.x;
    if (n >= DHALF * S3) return;
    int o = n / S3;
    int r = n - o * S3;
    int z = r / PLANE;
    int t = r - z * PLANE;
    int y = t / WW;
    int xx = t - y * WW;
    float acc = 0.f;
    #pragma unroll
    for (int ic = 0; ic < 2; ic++) {
        const float* ip = in + (size_t)(2 * o + ic) * S3;
        const float* wp = w + (o * 2 + ic) * 27;
        #pragma unroll
        for (int dz = 0; dz < 3; dz++) {
            int zz = z + dz - 1;
            if (zz < 0 || zz >= NBD) continue;
            #pragma unroll
            for (int dy = 0; dy < 3; dy++) {
                int yy = y + dy - 1;
                if (yy < 0 || yy >= HH) continue;
                #pragma unroll
                for (int dx = 0; dx < 3; dx++) {
                    int xc = xx + dx - 1;
                    if (xc < 0 || xc >= WW) continue;
                    acc += ip[zz * PLANE + yy * WW + xc] * wp[dz * 9 + dy * 3 + dx];
                }
            }
        }
    }
    outp[n] = acc;
}

// =====================================================================
// Kernel 3b: dual grouped 3x3x3 conv — same input, two weight sets
// =====================================================================
__global__ __launch_bounds__(256) void conv3_dual_kernel(
    const float* __restrict__ in,
    const float* __restrict__ wk, const float* __restrict__ wv,
    float* __restrict__ outk, float* __restrict__ outv)
{
    int n = blockIdx.x * 256 + threadIdx.x;
    if (n >= DHALF * S3) return;
    int o = n / S3;
    int r = n - o * S3;
    int z = r / PLANE;
    int t = r - z * PLANE;
    int y = t / WW;
    int xx = t - y * WW;
    float acck = 0.f, accv = 0.f;
    #pragma unroll
    for (int ic = 0; ic < 2; ic++) {
        const float* ip  = in + (size_t)(2 * o + ic) * S3;
        const float* wpk = wk + (o * 2 + ic) * 27;
        const float* wpv = wv + (o * 2 + ic) * 27;
        #pragma unroll
        for (int dz = 0; dz < 3; dz++) {
            int zz = z + dz - 1;
            if (zz < 0 || zz >= NBD) continue;
            #pragma unroll
            for (int dy = 0; dy < 3; dy++) {
                int yy = y + dy - 1;
                if (yy < 0 || yy >= HH) continue;
                #pragma unroll
                for (int dx = 0; dx < 3; dx++) {
                    int xc = xx + dx - 1;
                    if (xc < 0 || xc >= WW) continue;
                    float iv = ip[zz * PLANE + yy * WW + xc];
                    acck += iv * wpk[dz * 9 + dy * 3 + dx];
                    accv += iv * wpv[dz * 9 + dy * 3 + dx];
                }
            }
        }
    }
    outk[n] = acck;
    outv[n] = accv;
}

// =====================================================================
// Kernel 4: SCA — windowed cross-attention on precomputed q,k,v
// (R10 math; t/t2/theta/softmax parallelized 4 lanes/row)
// =====================================================================
__global__ __launch_bounds__(256) void sca_kernel(
    const float* __restrict__ qb, const float* __restrict__ kb,
    const float* __restrict__ vb, const float* __restrict__ x1,
    const float* __restrict__ ocw,
    const float* __restrict__ pcqw, const float* __restrict__ pcqb,
    const float* __restrict__ pckw, const float* __restrict__ pckb,
    const float* __restrict__ m1,  const float* __restrict__ m2a,
    const float* __restrict__ m2b,
    float* __restrict__ x2)
{
    __shared__ float s_q[NTOK * QKP];
    __shared__ float s_k[NTOK * QKP];
    __shared__ float s_v[NTOK * QKP];
    __shared__ float s_sim[NTOK * SIMP];
    __shared__ float s_o[NTOK * DHALF];
    __shared__ float s_Sq[NTOK], s_Sk[NTOK], s_t[NTOK], s_t2[NTOK];
    __shared__ float s_theta;

    const int tid = threadIdx.x;
    const int b   = blockIdx.x & 7;
    const int win = blockIdx.x >> 3;
    const int y0  = (win / NWX) * 8;
    const int x0  = (win % NWX) * 8;

    for (int i = tid; i < NTOK * DHALF; i += 256) {
        int o = i >> 6, tok = i & 63;
        int g = ((o * NBD + b) * HH + y0 + (tok >> 3)) * WW + x0 + (tok & 7);
        s_q[tok * QKP + o] = qb[g];
        s_k[tok * QKP + o] = kb[g];
        s_v[tok * QKP + o] = vb[g];
    }
    __syncthreads();

    for (int h = 0; h < 2; h++) {
        const int ho = h * DHEAD;
        if (tid < NTOK) {
            float a = pcqb[0];
            #pragma unroll
            for (int d = 0; d < DHEAD; d++) a += s_q[tid * QKP + ho + d] * pcqw[d];
            s_Sq[tid] = a;
        } else if (tid < 2 * NTOK) {
            int j = tid - NTOK;
            float a = pckb[0];
            #pragma unroll
            for (int d = 0; d < DHEAD; d++) a += s_k[j * QKP + ho + d] * pckw[d];
            s_Sk[j] = a;
        }
        __syncthreads();
        for (int i = tid; i < NTOK * NTOK; i += 256) {
            int r = i >> 6, j = i & 63;
            float a = 0.f;
            #pragma unroll
            for (int d = 0; d < DHEAD; d++)
                a += s_q[r * QKP + ho + d] * s_k[j * QKP + ho + d];
            s_sim[r * SIMP + j] = a;
        }
        __syncthreads();
        {
            const int r = tid >> 2, sub = tid & 3;
            float a = 0.f;
            #pragma unroll
            for (int jj = 0; jj < 16; jj++) {
                int j = sub * 16 + jj;
                a += (j != r) ? s_sim[r * SIMP + j] * m1[j] : 0.f;
            }
            a += __shfl_xor(a, 1); a += __shfl_xor(a, 2);
            if (sub == 0) s_t[r] = a;
        }
        __syncthreads();
        {
            const int r = tid >> 2, sub = tid & 3;
            float a = 0.f;
            #pragma unroll
            for (int jj = 0; jj < 16; jj++) {
                int i2 = sub * 16 + jj;
                a += s_t[i2] * m2a[r * 64 + i2];
            }
            a += __shfl_xor(a, 1); a += __shfl_xor(a, 2);
            if (sub == 0) s_t2[r] = (a > 0.f) ? a : 0.1f * a;
        }
        __syncthreads();
        if (tid < 64) {
            float a = s_t2[tid] * m2b[tid];
            #pragma unroll
            for (int off = 1; off < 64; off <<= 1) a += __shfl_xor(a, off);
            if (tid == 0) s_theta = a;
        }
        __syncthreads();
        {
            const int r = tid >> 2, sub = tid & 3;
            const float Sqi = s_Sq[r];
            const float th = s_theta;
            float vals[16];
            float m = -1e30f;
            #pragma unroll
            for (int jj = 0; jj < 16; jj++) {
                float s = s_sim[r * SIMP + sub * 16 + jj] * Sqi * s_Sk[sub * 16 + jj];
                vals[jj] = s;
                m = fmaxf(m, s);
            }
            m = fmaxf(m, __shfl_xor(m, 1));
            m = fmaxf(m, __shfl_xor(m, 2));
            float sum = 0.f;
            #pragma unroll
            for (int jj = 0; jj < 16; jj++) {
                float e = expf(vals[jj] - m);
                sum += e;
                vals[jj] = (vals[jj] > th) ? e : 0.f;
            }
            sum += __shfl_xor(sum, 1); sum += __shfl_xor(sum, 2);
            const float inv = 1.f / sum;
            #pragma unroll
            for (int jj = 0; jj < 16; jj++)
                s_sim[r * SIMP + sub * 16 + jj] = vals[jj] * inv;
        }
        __syncthreads();
        for (int i = tid; i < NTOK * DHEAD; i += 256) {
            int r = i / DHEAD, d = i - r * DHEAD;
            float a = 0.f;
            #pragma unroll
            for (int j = 0; j < NTOK; j++)
                a += s_sim[r * SIMP + j] * s_v[j * QKP + ho + d];
            s_o[r * DHALF + ho + d] = a;
        }
        __syncthreads();
    }

    for (int i = tid; i < NTOK * CH; i += 256) {
        int c = i >> 6, tok = i & 63;
        int g = gidx(c, b, y0 + (tok >> 3), x0 + (tok & 7));
        x2[g] = s_o[tok * DHALF + (c >> 1)] * ocw[c] + x1[g];
    }
}

// =====================================================================
// Kernel 5a: collapse FFN weights + emit pre-swizzled bf16 A-fragments.
// =====================================================================
__global__ __launch_bounds__(256) void ffn_wprep_frag_kernel(
    const float* __restrict__ w1x, const float* __restrict__ w2x,
    const float* __restrict__ w1l, const float* __restrict__ w2l,
    unsigned short* __restrict__ wfrag)
{
    int idx = blockIdx.x * 256 + threadIdx.x;     // (f, lane)
    if (idx >= 144 * 64) return;
    int f = idx >> 6, lane = idx & 63;
    int br = f / 72;
    int r  = f - br * 72;
    int tap = r >> 3;
    int m   = (r & 7) >> 1;
    int ks  = r & 1;
    const float* w1 = br ? w1l : w1x;
    const float* w2 = br ? w2l : w2x;
    int o  = m * 16 + (lane & 15);
    int c0 = ks * 32 + (lane >> 4) * 8;
    unsigned short vals[8];
    #pragma unroll
    for (int j = 0; j < 8; j++) {
        int c = c0 + j;
        float a = 0.f;
        if (o < 56 && c < 56) {
            #pragma unroll
            for (int jj = 0; jj < 4; jj++)
                a += w2[(o * 4 + jj) * 9 + tap] * w1[(o * 4 + jj) * 56 + c];
        }
        vals[j] = f2bf(a);
    }
    uint4 packed;
    packed.x = (unsigned int)vals[0] | ((unsigned int)vals[1] << 16);
    packed.y = (unsigned int)vals[2] | ((unsigned int)vals[3] << 16);
    packed.z = (unsigned int)vals[4] | ((unsigned int)vals[5] << 16);
    packed.w = (unsigned int)vals[6] | ((unsigned int)vals[7] << 16);
    *(uint4*)(wfrag + (size_t)idx * 8) = packed;
}

// =====================================================================
// Kernel 5b: FFN via MFMA — 9 shifted GEMMs on bf16 LN'd inputs.
// =====================================================================
__global__ __launch_bounds__(256) void ffn_mfma_kernel(
    const unsigned short* __restrict__ xnb,   // LN'd x2, bf16 [p][56]
    const unsigned short* __restrict__ lnb,   // LN'd last, bf16 [p][56]
    const unsigned short* __restrict__ wfrag, // A-fragments
    const float* __restrict__ x2,             // residual fp32 [c][p]
    float* __restrict__ outp)
{
    __shared__ unsigned short s_t[2 * 100 * 64];   // 25.6 KB

    const int tid = threadIdx.x;
    const int z  = blockIdx.x / 576;
    const int t  = blockIdx.x % 576;
    const int ty = t / 24, tx = t % 24;
    const int y0 = ty * 8, x0 = tx * 8;

    for (int i = tid; i < 1600; i += 256) {
        int br = i / 800;
        int r  = i - br * 800;
        int hp = r >> 3, ck = r & 7;
        int hy = hp / 10, hx = hp - hy * 10;
        int y = y0 + hy - 1, xx = x0 + hx - 1;
        uint4 v = {0u, 0u, 0u, 0u};
        if (ck < 7 && y >= 0 && y < HH && xx >= 0 && xx < WW) {
            const unsigned short* src = (br ? lnb : xnb) +
                (size_t)(z * PLANE + y * WW + xx) * 56 + ck * 8;
            v = *(const uint4*)src;
        }
        unsigned int byte = (unsigned int)(br * FFN_BR_OFF + hp * 128 + ((ck ^ (hp & 7)) << 4));
        *(uint4*)((char*)s_t + byte) = v;
    }
    __syncthreads();

    const int wid  = tid >> 6;
    const int lane = tid & 63;
    const int col  = lane & 15;
    const int grp  = lane >> 4;

    f32x4 accx[4], accl[4];
    #pragma unroll
    for (int n = 0; n < 4; n++) {
        accx[n] = (f32x4){0.f, 0.f, 0.f, 0.f};
        accl[n] = (f32x4){0.f, 0.f, 0.f, 0.f};
    }

    const short8* wf = (const short8*)wfrag;

    for (int tap = 0; tap < 9; tap++) {
        int dy = tap / 3, dx = tap - dy * 3;
        short8 ax0 = wf[(tap * 8 + wid * 2 + 0) * 64 + lane];
        short8 ax1 = wf[(tap * 8 + wid * 2 + 1) * 64 + lane];
        short8 al0 = wf[(72 + tap * 8 + wid * 2 + 0) * 64 + lane];
        short8 al1 = wf[(72 + tap * 8 + wid * 2 + 1) * 64 + lane];
        #pragma unroll
        for (int nt = 0; nt < 4; nt++) {
            int pix = nt * 16 + col;
            int py = pix >> 3, px = pix & 7;
            int hp = (py + dy) * 10 + (px + dx);
            unsigned int base = (unsigned int)(hp * 128);
            unsigned int sw = (unsigned int)(hp & 7);
            unsigned int o0 = base + ((grp ^ sw) << 4);
            short8 bx0 = *(const short8*)((const char*)s_t + o0);
            short8 bl0 = *(const short8*)((const char*)s_t + FFN_BR_OFF + o0);
            accx[nt] = __builtin_amdgcn_mfma_f32_16x16x32_bf16(ax0, bx0, accx[nt], 0, 0, 0);
            accl[nt] = __builtin_amdgcn_mfma_f32_16x16x32_bf16(al0, bl0, accl[nt], 0, 0, 0);
            unsigned int o1 = base + (((4u + grp) ^ sw) << 4);
            short8 bx1 = *(const short8*)((const char*)s_t + o1);
            short8 bl1 = *(const short8*)((const char*)s_t + FFN_BR_OFF + o1);
            accx[nt] = __builtin_amdgcn_mfma_f32_16x16x32_bf16(ax1, bx1, accx[nt], 0, 0, 0);
            accl[nt] = __builtin_amdgcn_mfma_f32_16x16x32_bf16(al1, bl1, accl[nt], 0, 0, 0);
        }
    }

    #pragma unroll
    for (int nt = 0; nt < 4; nt++) {
        int pix = nt * 16 + col;
        int py = pix >> 3, px = pix & 7;
        int p = z * PLANE + (y0 + py) * WW + (x0 + px);
        #pragma unroll
        for (int reg = 0; reg < 4; reg++) {
            int o = wid * 16 + grp * 4 + reg;
            if (o < 56) {
                float lv = accl[nt][reg];
                float ge = 0.5f * lv * (1.f + erff(lv * 0.70710678118654752f));
                size_t g = (size_t)o * S3 + p;
                outp[g] = accx[nt][reg] * ge + x2[g];
            }
        }
    }
}

// =====================================================================
extern "C" void kernel_launch(void* const* d_in, const int* in_sizes, int n_in,
                              void* d_out, int out_size, void* d_ws, size_t ws_size,
                              hipStream_t stream)
{
    (void)in_sizes; (void)n_in; (void)out_size; (void)ws_size;
    const float* x         = (const float*)d_in[0];
    const float* last      = (const float*)d_in[1];
    const float* fa_ln_w   = (const float*)d_in[2];
    const float* fa_ln_b   = (const float*)d_in[3];
    const float* fa_qk_w   = (const float*)d_in[4];
    const float* fa_v_w    = (const float*)d_in[5];
    const float* fa_out_w  = (const float*)d_in[6];
    const float* fa_out_b  = (const float*)d_in[7];
    const float* fa_pcq_w  = (const float*)d_in[8];
    const float* fa_pcq_b  = (const float*)d_in[9];
    const float* fa_pck_w  = (const float*)d_in[10];
    const float* fa_pck_b  = (const float*)d_in[11];
    const float* fa_m1_w   = (const float*)d_in[12];
    const float* fa_m2a_w  = (const float*)d_in[13];
    const float* fa_m2b_w  = (const float*)d_in[14];
    const float* sca_ln1_w = (const float*)d_in[15];
    const float* sca_ln1_b = (const float*)d_in[16];
    const float* sca_ln2_w = (const float*)d_in[17];
    const float* sca_ln2_b = (const float*)d_in[18];
    const float* sca_q_w   = (const float*)d_in[19];
    const float* sca_k_w   = (const float*)d_in[20];
    const float* sca_v_w   = (const float*)d_in[21];
    const float* sca_out_w = (const float*)d_in[22];
    const float* sca_pcq_w = (const float*)d_in[23];
    const float* sca_pcq_b = (const float*)d_in[24];
    const float* sca_pck_w = (const float*)d_in[25];
    const float* sca_pck_b = (const float*)d_in[26];
    const float* sca_m1_w  = (const float*)d_in[27];
    const float* sca_m2a_w = (const float*)d_in[28];
    const float* sca_m2b_w = (const float*)d_in[29];
    const float* ffn_ln1_w = (const float*)d_in[30];
    const float* ffn_ln1_b = (const float*)d_in[31];
    const float* ffn_ln2_w = (const float*)d_in[32];
    const float* ffn_ln2_b = (const float*)d_in[33];
    const float* ffn_x1_w  = (const float*)d_in[34];
    const float* ffn_x2_w  = (const float*)d_in[35];
    const float* ffn_l1_w  = (const float*)d_in[36];
    const float* ffn_l2_w  = (const float*)d_in[37];
    float* out = (float*)d_out;
    float* ws  = (float*)d_ws;

    const size_t FULL = (size_t)CH * S3;      // 16,515,072 floats
    const size_t HALF = (size_t)DHALF * S3;
    float* x1    = ws;                        // FA output (freed after sca)
    float* lnbuf = ws + FULL;                 // LN scratch -> x2
    float* qb    = lnbuf + FULL;
    float* kb    = qb + HALF;
    float* vb    = kb + HALF;
    unsigned short* wfrag = (unsigned short*)(vb + HALF);  // 147 KB
    float* x2    = lnbuf;
    unsigned short* xnb  = (unsigned short*)ws;        // bytes [0, 33MB)
    unsigned short* lnbb = (unsigned short*)ws + FULL; // bytes [33MB, 66MB)

    // --- FFN weight fragments (independent) ---
    ffn_wprep_frag_kernel<<<dim3(36), dim3(256), 0, stream>>>(
        ffn_x1_w, ffn_x2_w, ffn_l1_w, ffn_l2_w, wfrag);

    // --- FA ---
    fa_kernel<<<dim3(4608), dim3(256), 0, stream>>>(
        x, fa_ln_w, fa_ln_b, fa_qk_w, fa_v_w, fa_out_w, fa_out_b,
        fa_pcq_w, fa_pcq_b, fa_pck_w, fa_pck_b, fa_m1_w, fa_m2a_w, fa_m2b_w, x1);

    // --- SCA: LN + grouped convs (k+v merged: one pass over LN'd last) ---
    ln_kernel<<<dim3(S3 / 256), dim3(256), 0, stream>>>(x1, sca_ln1_w, sca_ln1_b, lnbuf);
    conv3_kernel<<<dim3(DHALF * S3 / 256), dim3(256), 0, stream>>>(lnbuf, sca_q_w, qb);
    ln_kernel<<<dim3(S3 / 256), dim3(256), 0, stream>>>(last, sca_ln2_w, sca_ln2_b, lnbuf);
    conv3_dual_kernel<<<dim3(DHALF * S3 / 256), dim3(256), 0, stream>>>(
        lnbuf, sca_k_w, sca_v_w, kb, vb);

    sca_kernel<<<dim3(4608), dim3(256), 0, stream>>>(
        qb, kb, vb, x1, sca_out_w,
        sca_pcq_w, sca_pcq_b, sca_pck_w, sca_pck_b, sca_m1_w, sca_m2a_w, sca_m2b_w, x2);

    // --- FFN: LN->bf16, then MFMA conv ---
    ln_bf16_kernel<<<dim3(S3 / 256), dim3(256), 0, stream>>>(x2,   ffn_ln1_w, ffn_ln1_b, xnb);
    ln_bf16_kernel<<<dim3(S3 / 256), dim3(256), 0, stream>>>(last, ffn_ln2_w, ffn_ln2_b, lnbb);
    ffn_mfma_kernel<<<dim3(4608), dim3(256), 0, stream>>>(xnb, lnbb, wfrag, x2, out);
}